// Round 5
// baseline (296.669 us; speedup 1.0000x reference)
//
#include <hip/hip_runtime.h>

// GIN block, 2 layers: h = mlp(h + segsum(h[src], dst)); out = (h*mask, x)
// N=100000, E=1600000, D=64.
// Round-5: same structure as round 4 (atomic-free bucket build + bf16 8-deep gather),
// MLP rewritten with NAMED float4 accumulators (macro-expanded) -- no arrays at all,
// so nothing can be demoted to scratch (round-4 mlp: VGPR=40 => a[64] spilled, 100us).

#define NN 100000
#define EE 1600000
#define CAP 48
#define NBIN 1024          // used: 0..781
#define CHB 6250           // EE / 256 blocks
#define OVF_CAPN 8000

// ws layout (ints):
//   binTot   @ 0        (1024)               -- memset 0
//   ovfCnt   @ 1024     (1)                  -- memset 0 (memset covers [0,2048))
//   ovf      @ 1026     (2*8000)
//   binStart @ 17056    (1025)
//   cursor   @ 18112    (1024)
//   cnt      @ 19200    (100000)
//   bucket   @ 119296   (NN*CAP = 4800000)
//   binned   @ 4919296  (EE)        } aliased: binned dead after bucketize,
//   hb/hb1   @ 4919296  (3200000)   } then region holds bf16 h / bf16 h1
#define OVFC_OFF   1024
#define OVF_OFF    1026
#define BSTART_OFF 17056
#define CURSOR_OFF 18112
#define CNT_OFF    19200
#define BUCK_OFF   119296
#define BINNED_OFF 4919296
#define HB_OFF     4919296

static __device__ __forceinline__ unsigned short f2bf(float f) {
  unsigned u = __float_as_uint(f);
  return (unsigned short)((u + 0x7FFF + ((u >> 16) & 1)) >> 16);  // RTNE
}
static __device__ __forceinline__ float bf2f(unsigned short s) {
  return __uint_as_float(((unsigned)s) << 16);
}
static __device__ __forceinline__ unsigned pk2(float lo, float hi) {
  return (unsigned)f2bf(lo) | ((unsigned)f2bf(hi) << 16);
}
static __device__ __forceinline__ float4 fma4(float s, float4 w, float4 a) {
  return make_float4(fmaf(s, w.x, a.x), fmaf(s, w.y, a.y),
                     fmaf(s, w.z, a.z), fmaf(s, w.w, a.w));
}
static __device__ __forceinline__ float4 relu4(float4 a) {
  return make_float4(fmaxf(a.x, 0.f), fmaxf(a.y, 0.f), fmaxf(a.z, 0.f), fmaxf(a.w, 0.f));
}

#define Q16(M) M(0) M(1) M(2) M(3) M(4) M(5) M(6) M(7) M(8) M(9) M(10) M(11) M(12) M(13) M(14) M(15)
#define Q8(M)  M(0) M(1) M(2) M(3) M(4) M(5) M(6) M(7)

__global__ __launch_bounds__(256) void hist_k(const int* __restrict__ dst,
                                              int* __restrict__ binTot) {
  __shared__ int hist[NBIN];
  const int t = threadIdx.x;
#pragma unroll
  for (int b = t; b < NBIN; b += 256) hist[b] = 0;
  __syncthreads();
  const int s = blockIdx.x * CHB;
#pragma unroll 1
  for (int i = s + t; i < s + CHB; i += 256) atomicAdd(&hist[dst[i] >> 7], 1);
  __syncthreads();
#pragma unroll
  for (int b = t; b < NBIN; b += 256) {
    const int c = hist[b];
    if (c) atomicAdd(&binTot[b], c);
  }
}

__global__ __launch_bounds__(1024) void scan_k(const int* __restrict__ binTot,
                                               int* __restrict__ binStart,
                                               int* __restrict__ cursor) {
  __shared__ int sh[NBIN];
  const int t = threadIdx.x;
  const int v = binTot[t];
  sh[t] = v;
  __syncthreads();
  for (int off = 1; off < NBIN; off <<= 1) {
    const int x = (t >= off) ? sh[t - off] : 0;
    __syncthreads();
    sh[t] += x;
    __syncthreads();
  }
  binStart[t] = sh[t] - v;
  cursor[t] = sh[t] - v;
  if (t == NBIN - 1) binStart[NBIN] = sh[t];
}

__global__ __launch_bounds__(256) void scatter_k(const int* __restrict__ src,
                                                 const int* __restrict__ dst,
                                                 int* __restrict__ cursor,
                                                 int* __restrict__ binned) {
  __shared__ int hist[NBIN], base[NBIN], lcnt[NBIN];
  const int t = threadIdx.x;
#pragma unroll
  for (int b = t; b < NBIN; b += 256) { hist[b] = 0; lcnt[b] = 0; }
  __syncthreads();
  const int s = blockIdx.x * CHB;
#pragma unroll 1
  for (int i = s + t; i < s + CHB; i += 256) atomicAdd(&hist[dst[i] >> 7], 1);
  __syncthreads();
#pragma unroll
  for (int b = t; b < NBIN; b += 256) {
    const int c = hist[b];
    base[b] = c ? atomicAdd(&cursor[b], c) : 0;
  }
  __syncthreads();
#pragma unroll 1
  for (int i = s + t; i < s + CHB; i += 256) {
    const int d = dst[i], sv = src[i];
    const int bin = d >> 7;
    const int off = atomicAdd(&lcnt[bin], 1);
    binned[base[bin] + off] = ((d & 127) << 17) | sv;  // src < 2^17
  }
}

__global__ __launch_bounds__(256) void bucketize_k(const int* __restrict__ binStart,
                                                   const int* __restrict__ binned,
                                                   int* __restrict__ bucket,
                                                   int* __restrict__ cnt,
                                                   int* __restrict__ ovf) {
  __shared__ int c128[128];
  const int t = threadIdx.x;
  const int bin = blockIdx.x;
  const int nbase = bin << 7;
  if (t < 128) c128[t] = 0;
  __syncthreads();
  const int s0 = binStart[bin], s1 = binStart[bin + 1];
#pragma unroll 1
  for (int i = s0 + t; i < s1; i += 256) {
    const int p = binned[i];
    const int dlow = p >> 17;
    const int sv = p & 131071;
    const int slot = atomicAdd(&c128[dlow], 1);
    if (slot < CAP) {
      bucket[(nbase + dlow) * CAP + slot] = sv;
    } else {
      const int q = atomicAdd(&ovf[-2], 1);  // ovf[-2] == ovfCnt
      if (q < OVF_CAPN) { ovf[2 * q] = nbase + dlow; ovf[2 * q + 1] = sv; }
    }
  }
  __syncthreads();
  if (t < 128 && nbase + t < NN) cnt[nbase + t] = c128[t];
}

// h (f32) -> hb (bf16), 8 elems/thread
__global__ __launch_bounds__(256) void cvt_k(const float* __restrict__ h,
                                             unsigned* __restrict__ hb) {
  const int i = blockIdx.x * blockDim.x + threadIdx.x;
  if (i >= NN * 8) return;  // 800000
  const float4* __restrict__ h4 = reinterpret_cast<const float4*>(h);
  const float4 a = h4[2 * i], b = h4[2 * i + 1];
  uint4 o;
  o.x = pk2(a.x, a.y); o.y = pk2(a.z, a.w);
  o.z = pk2(b.x, b.y); o.w = pk2(b.z, b.w);
  reinterpret_cast<uint4*>(hb)[i] = o;
}

// z[n] = hb[n] + sum_{j->n} hb[j]  (wave-per-node, 8 loads in flight, bf16 rows)
__global__ __launch_bounds__(256) void agg_k(const unsigned short* __restrict__ hb,
                                             const int* __restrict__ cnt,
                                             const int* __restrict__ bucket,
                                             float* __restrict__ z) {
  const int l = threadIdx.x & 63;
  int n = blockIdx.x * (blockDim.x >> 6) + (threadIdx.x >> 6);
  if (n >= NN) return;
  n = __builtin_amdgcn_readfirstlane(n);
  const int deg = min(cnt[n], CAP);
  const int* __restrict__ brow = bucket + n * CAP;
  float acc = bf2f(hb[(n << 6) | l]);
#pragma unroll 1
  for (int e = 0; e < deg; e += 8) {
    const int4 qa = *reinterpret_cast<const int4*>(brow + e);
    const int4 qb = *reinterpret_cast<const int4*>(brow + e + 4);
    const int s0 = qa.x;
    const int s1 = (e + 1 < deg) ? qa.y : s0;
    const int s2 = (e + 2 < deg) ? qa.z : s0;
    const int s3 = (e + 3 < deg) ? qa.w : s0;
    const int s4 = (e + 4 < deg) ? qb.x : s0;
    const int s5 = (e + 5 < deg) ? qb.y : s0;
    const int s6 = (e + 6 < deg) ? qb.z : s0;
    const int s7 = (e + 7 < deg) ? qb.w : s0;
    const float v0 = bf2f(hb[(s0 << 6) | l]);
    const float v1 = bf2f(hb[(s1 << 6) | l]);
    const float v2 = bf2f(hb[(s2 << 6) | l]);
    const float v3 = bf2f(hb[(s3 << 6) | l]);
    const float v4 = bf2f(hb[(s4 << 6) | l]);
    const float v5 = bf2f(hb[(s5 << 6) | l]);
    const float v6 = bf2f(hb[(s6 << 6) | l]);
    const float v7 = bf2f(hb[(s7 << 6) | l]);
    const float w1 = (e + 1 < deg) ? v1 : 0.f;
    const float w2 = (e + 2 < deg) ? v2 : 0.f;
    const float w3 = (e + 3 < deg) ? v3 : 0.f;
    const float w4 = (e + 4 < deg) ? v4 : 0.f;
    const float w5 = (e + 5 < deg) ? v5 : 0.f;
    const float w6 = (e + 6 < deg) ? v6 : 0.f;
    const float w7 = (e + 7 < deg) ? v7 : 0.f;
    acc += ((v0 + w1) + (w2 + w3)) + ((w4 + w5) + (w6 + w7));
  }
  z[(n << 6) | l] = acc;
}

__global__ __launch_bounds__(256) void ovf_fix_k(const unsigned short* __restrict__ hb,
                                                 float* __restrict__ z,
                                                 const int* __restrict__ ovfCnt,
                                                 const int* __restrict__ ovf) {
  const int cv = min(ovfCnt[0], OVF_CAPN);
  const int l = threadIdx.x & 63;
  const int w = threadIdx.x >> 6;
  for (int p = w; p < cv; p += 4) {
    const int d = ovf[2 * p];
    const int s = ovf[2 * p + 1];
    atomicAdd(&z[(d << 6) | l], bf2f(hb[(s << 6) | l]));
  }
}

// Per-node MLP, named-float4 accumulators only (no arrays -> no scratch).
// out = relu(z@W1+b1)@W2+b2; OUTBF: write packed bf16 rows; MASK: f32 * mask.
template <int OUTBF, int MASK>
__global__ __launch_bounds__(256) void mlp_k(
    const float* __restrict__ z, void* __restrict__ hout,
    const float* __restrict__ W1, const float* __restrict__ b1,
    const float* __restrict__ W2, const float* __restrict__ b2,
    const float* __restrict__ mask) {
  const int n = blockIdx.x * blockDim.x + threadIdx.x;
  if (n >= NN) return;
  const float4* __restrict__ W1v = reinterpret_cast<const float4*>(W1);
  const float4* __restrict__ W2v = reinterpret_cast<const float4*>(W2);
  const float4* __restrict__ b1v = reinterpret_cast<const float4*>(b1);
  const float4* __restrict__ b2v = reinterpret_cast<const float4*>(b2);
  const float4* __restrict__ zrow = reinterpret_cast<const float4*>(z) + (n << 4);

  // ---- GEMM1: A(q) accumulate 64 outputs, runtime k4 loop (loop-carried SSA) ----
#define DECLA(q) float4 A##q = b1v[q];
  Q16(DECLA)
#undef DECLA
#pragma unroll 1
  for (int k4 = 0; k4 < 16; ++k4) {
    const float4 zv = zrow[k4];
    const float4* __restrict__ w_ = W1v + k4 * 64;  // rows k4*4 .. k4*4+3
#define G1(q)                             \
    A##q = fma4(zv.x, w_[q], A##q);       \
    A##q = fma4(zv.y, w_[16 + q], A##q);  \
    A##q = fma4(zv.z, w_[32 + q], A##q);  \
    A##q = fma4(zv.w, w_[48 + q], A##q);
    Q16(G1)
#undef G1
  }
#define RELU(q) A##q = relu4(A##q);
  Q16(RELU)
#undef RELU

  float m = 1.f;
  if (MASK) m = mask[n];

  // ---- GEMM2: two halves of 32 output cols; fully static (A##k4 referenced) ----
#define G2J(s_, wj)                                                   \
  C0 = fma4(s_, (wj)[0], C0); C1 = fma4(s_, (wj)[1], C1);             \
  C2 = fma4(s_, (wj)[2], C2); C3 = fma4(s_, (wj)[3], C3);             \
  C4 = fma4(s_, (wj)[4], C4); C5 = fma4(s_, (wj)[5], C5);             \
  C6 = fma4(s_, (wj)[6], C6); C7 = fma4(s_, (wj)[7], C7);
#define G2K(q)                                                        \
  { const float4 av_ = A##q;                                          \
    const float4* __restrict__ wk_ = W2h + (q) * 64;                  \
    G2J(av_.x, wk_) G2J(av_.y, wk_ + 16)                              \
    G2J(av_.z, wk_ + 32) G2J(av_.w, wk_ + 48) }

  {  // half 0: out cols 0..31
    const float4* __restrict__ W2h = W2v;
#define DECLC(q) float4 C##q = b2v[q];
    Q8(DECLC)
#undef DECLC
    Q16(G2K)
    if (OUTBF) {
      uint4* __restrict__ prow = reinterpret_cast<uint4*>(hout) + (n << 3);
      prow[0] = make_uint4(pk2(C0.x, C0.y), pk2(C0.z, C0.w), pk2(C1.x, C1.y), pk2(C1.z, C1.w));
      prow[1] = make_uint4(pk2(C2.x, C2.y), pk2(C2.z, C2.w), pk2(C3.x, C3.y), pk2(C3.z, C3.w));
      prow[2] = make_uint4(pk2(C4.x, C4.y), pk2(C4.z, C4.w), pk2(C5.x, C5.y), pk2(C5.z, C5.w));
      prow[3] = make_uint4(pk2(C6.x, C6.y), pk2(C6.z, C6.w), pk2(C7.x, C7.y), pk2(C7.z, C7.w));
    } else {
      float4* __restrict__ orow = reinterpret_cast<float4*>(hout) + (n << 4);
#define ST0(q) { float4 o; o.x = C##q.x * m; o.y = C##q.y * m; o.z = C##q.z * m; o.w = C##q.w * m; orow[q] = o; }
      Q8(ST0)
#undef ST0
    }
  }
  {  // half 1: out cols 32..63
    const float4* __restrict__ W2h = W2v + 8;
#define DECLC(q) float4 C##q = b2v[8 + q];
    Q8(DECLC)
#undef DECLC
    Q16(G2K)
    if (OUTBF) {
      uint4* __restrict__ prow = reinterpret_cast<uint4*>(hout) + (n << 3) + 4;
      prow[0] = make_uint4(pk2(C0.x, C0.y), pk2(C0.z, C0.w), pk2(C1.x, C1.y), pk2(C1.z, C1.w));
      prow[1] = make_uint4(pk2(C2.x, C2.y), pk2(C2.z, C2.w), pk2(C3.x, C3.y), pk2(C3.z, C3.w));
      prow[2] = make_uint4(pk2(C4.x, C4.y), pk2(C4.z, C4.w), pk2(C5.x, C5.y), pk2(C5.z, C5.w));
      prow[3] = make_uint4(pk2(C6.x, C6.y), pk2(C6.z, C6.w), pk2(C7.x, C7.y), pk2(C7.z, C7.w));
    } else {
      float4* __restrict__ orow = reinterpret_cast<float4*>(hout) + (n << 4) + 8;
#define ST1(q) { float4 o; o.x = C##q.x * m; o.y = C##q.y * m; o.z = C##q.z * m; o.w = C##q.w * m; orow[q] = o; }
      Q8(ST1)
#undef ST1
    }
  }
#undef G2K
#undef G2J
}

__global__ __launch_bounds__(256) void xcopy_k(const float* __restrict__ x,
                                               float* __restrict__ ox) {
  const int i = blockIdx.x * blockDim.x + threadIdx.x;
  if (i < (NN * 3) / 4) {
    reinterpret_cast<float4*>(ox)[i] = reinterpret_cast<const float4*>(x)[i];
  }
}

extern "C" void kernel_launch(void* const* d_in, const int* in_sizes, int n_in,
                              void* d_out, int out_size, void* d_ws, size_t ws_size,
                              hipStream_t stream) {
  (void)in_sizes; (void)n_in; (void)out_size; (void)ws_size;
  const float* h    = (const float*)d_in[0];
  const float* x    = (const float*)d_in[1];
  const int*   ei   = (const int*)d_in[2];
  const float* mask = (const float*)d_in[3];
  const float* W1_0 = (const float*)d_in[4];
  const float* b1_0 = (const float*)d_in[5];
  const float* W2_0 = (const float*)d_in[6];
  const float* b2_0 = (const float*)d_in[7];
  const float* W1_1 = (const float*)d_in[8];
  const float* b1_1 = (const float*)d_in[9];
  const float* W2_1 = (const float*)d_in[10];
  const float* b2_1 = (const float*)d_in[11];
  float* out = (float*)d_out;

  const int* src = ei;       // edge_index[0]
  const int* dst = ei + EE;  // edge_index[1]

  int* wsp       = (int*)d_ws;
  int* binTot    = wsp;
  int* ovfCnt    = wsp + OVFC_OFF;
  int* ovf       = wsp + OVF_OFF;
  int* binStart  = wsp + BSTART_OFF;
  int* cursor    = wsp + CURSOR_OFF;
  int* cnt       = wsp + CNT_OFF;
  int* bucket    = wsp + BUCK_OFF;
  int* binned    = wsp + BINNED_OFF;
  unsigned* hb   = (unsigned*)(wsp + HB_OFF);  // bf16 h table; later bf16 h1
  const unsigned short* hbs = (const unsigned short*)hb;
  float* z       = out;  // z staged in d_out's h region (mlp reads row before writing)

  // --- edge structure build (once, reused by both layers) ---
  hipMemsetAsync(d_ws, 0, 8192, stream);  // binTot + ovfCnt
  hist_k<<<256, 256, 0, stream>>>(dst, binTot);
  scan_k<<<1, 1024, 0, stream>>>(binTot, binStart, cursor);
  scatter_k<<<256, 256, 0, stream>>>(src, dst, cursor, binned);
  bucketize_k<<<782, 256, 0, stream>>>(binStart, binned, bucket, cnt, ovf);

  // --- layer 1 ---
  cvt_k<<<3125, 256, 0, stream>>>(h, hb);  // binned dead; region becomes hb
  agg_k<<<25000, 256, 0, stream>>>(hbs, cnt, bucket, z);
  ovf_fix_k<<<1, 256, 0, stream>>>(hbs, z, ovfCnt, ovf);
  mlp_k<1, 0><<<391, 256, 0, stream>>>(z, hb, W1_0, b1_0, W2_0, b2_0, nullptr);  // h1 -> bf16

  // --- layer 2 ---
  agg_k<<<25000, 256, 0, stream>>>(hbs, cnt, bucket, z);
  ovf_fix_k<<<1, 256, 0, stream>>>(hbs, z, ovfCnt, ovf);
  mlp_k<0, 1><<<391, 256, 0, stream>>>(z, out, W1_1, b1_1, W2_1, b2_1, mask);

  // --- x passthrough ---
  xcopy_k<<<293, 256, 0, stream>>>(x, out + NN * 64);
}

// Round 7
// 178.110 us; speedup vs baseline: 1.6657x; 1.6657x over previous
//
#include <hip/hip_runtime.h>

// GIN block, 2 layers: h = mlp(h + segsum(h[src], dst)); out = (h*mask, x)
// N=100000, E=1600000, D=64.
// Round-7: round-6 MFMA MLP with the LDS hand-off fixed:
//  - all LDS traffic is plain `unsigned` scalar ops (no cross-type punning / TBAA hazard)
//  - explicit __syncthreads() between GEMM1-pack-write and GEMM2-fragment-read
//  - epilogues write directly from C/D fragments (no LDS staging at all)
// Build chain (hist/scan/scatter/bucketize), cvt, bf16 8-deep agg unchanged from round 5.

#define NN 100000
#define EE 1600000
#define CAP 48
#define NBIN 1024
#define CHB 6250
#define OVF_CAPN 8000

// ws layout (ints):
//   binTot   @ 0        (1024)   -- memset 0
//   ovfCnt   @ 1024     (1)      -- memset 0
//   ovf      @ 1026     (2*8000)
//   binStart @ 17056    (1025)
//   cursor   @ 18112    (1024)
//   cnt      @ 19200    (100000)
//   bucket   @ 119296   (NN*CAP)
//   binned   @ 4919296  (EE)       } binned dead after bucketize ->
//   hb/hb1   @ 4919296  (3200000)  } region becomes bf16 h / bf16 h1
//   pw       @ 8119296  (16384 shorts = 4 x 4096)
#define OVFC_OFF   1024
#define OVF_OFF    1026
#define BSTART_OFF 17056
#define CURSOR_OFF 18112
#define CNT_OFF    19200
#define BUCK_OFF   119296
#define BINNED_OFF 4919296
#define HB_OFF     4919296
#define PW_OFF     8119296

typedef __attribute__((ext_vector_type(8))) short s8v;
typedef __attribute__((ext_vector_type(4))) float f4v;

union U8 { unsigned u[4]; s8v s; };

static __device__ __forceinline__ unsigned short f2bf(float f) {
  unsigned u = __float_as_uint(f);
  return (unsigned short)((u + 0x7FFF + ((u >> 16) & 1)) >> 16);  // RTNE
}
static __device__ __forceinline__ float bf2f(unsigned short s) {
  return __uint_as_float(((unsigned)s) << 16);
}
static __device__ __forceinline__ unsigned pk2(float lo, float hi) {
  return (unsigned)f2bf(lo) | ((unsigned)f2bf(hi) << 16);
}

__global__ __launch_bounds__(256) void hist_k(const int* __restrict__ dst,
                                              int* __restrict__ binTot) {
  __shared__ int hist[NBIN];
  const int t = threadIdx.x;
#pragma unroll
  for (int b = t; b < NBIN; b += 256) hist[b] = 0;
  __syncthreads();
  const int s = blockIdx.x * CHB;
#pragma unroll 1
  for (int i = s + t; i < s + CHB; i += 256) atomicAdd(&hist[dst[i] >> 7], 1);
  __syncthreads();
#pragma unroll
  for (int b = t; b < NBIN; b += 256) {
    const int c = hist[b];
    if (c) atomicAdd(&binTot[b], c);
  }
}

__global__ __launch_bounds__(1024) void scan_k(const int* __restrict__ binTot,
                                               int* __restrict__ binStart,
                                               int* __restrict__ cursor) {
  __shared__ int sh[NBIN];
  const int t = threadIdx.x;
  const int v = binTot[t];
  sh[t] = v;
  __syncthreads();
  for (int off = 1; off < NBIN; off <<= 1) {
    const int x = (t >= off) ? sh[t - off] : 0;
    __syncthreads();
    sh[t] += x;
    __syncthreads();
  }
  binStart[t] = sh[t] - v;
  cursor[t] = sh[t] - v;
  if (t == NBIN - 1) binStart[NBIN] = sh[t];
}

__global__ __launch_bounds__(256) void scatter_k(const int* __restrict__ src,
                                                 const int* __restrict__ dst,
                                                 int* __restrict__ cursor,
                                                 int* __restrict__ binned) {
  __shared__ int hist[NBIN], base[NBIN], lcnt[NBIN];
  const int t = threadIdx.x;
#pragma unroll
  for (int b = t; b < NBIN; b += 256) { hist[b] = 0; lcnt[b] = 0; }
  __syncthreads();
  const int s = blockIdx.x * CHB;
#pragma unroll 1
  for (int i = s + t; i < s + CHB; i += 256) atomicAdd(&hist[dst[i] >> 7], 1);
  __syncthreads();
#pragma unroll
  for (int b = t; b < NBIN; b += 256) {
    const int c = hist[b];
    base[b] = c ? atomicAdd(&cursor[b], c) : 0;
  }
  __syncthreads();
#pragma unroll 1
  for (int i = s + t; i < s + CHB; i += 256) {
    const int d = dst[i], sv = src[i];
    const int bin = d >> 7;
    const int off = atomicAdd(&lcnt[bin], 1);
    binned[base[bin] + off] = ((d & 127) << 17) | sv;  // src < 2^17
  }
}

__global__ __launch_bounds__(256) void bucketize_k(const int* __restrict__ binStart,
                                                   const int* __restrict__ binned,
                                                   int* __restrict__ bucket,
                                                   int* __restrict__ cnt,
                                                   int* __restrict__ ovf) {
  __shared__ int c128[128];
  const int t = threadIdx.x;
  const int bin = blockIdx.x;
  const int nbase = bin << 7;
  if (t < 128) c128[t] = 0;
  __syncthreads();
  const int s0 = binStart[bin], s1 = binStart[bin + 1];
#pragma unroll 1
  for (int i = s0 + t; i < s1; i += 256) {
    const int p = binned[i];
    const int dlow = p >> 17;
    const int sv = p & 131071;
    const int slot = atomicAdd(&c128[dlow], 1);
    if (slot < CAP) {
      bucket[(nbase + dlow) * CAP + slot] = sv;
    } else {
      const int q = atomicAdd(&ovf[-2], 1);  // ovf[-2] == ovfCnt
      if (q < OVF_CAPN) { ovf[2 * q] = nbase + dlow; ovf[2 * q + 1] = sv; }
    }
  }
  __syncthreads();
  if (t < 128 && nbase + t < NN) cnt[nbase + t] = c128[t];
}

// h (f32) -> hb (bf16 contiguous 128B rows)
__global__ __launch_bounds__(256) void cvt_k(const float* __restrict__ h,
                                             unsigned* __restrict__ hb) {
  const int i = blockIdx.x * blockDim.x + threadIdx.x;
  if (i >= NN * 8) return;
  const float4* __restrict__ h4 = reinterpret_cast<const float4*>(h);
  const float4 a = h4[2 * i], b = h4[2 * i + 1];
  uint4 o;
  o.x = pk2(a.x, a.y); o.y = pk2(a.z, a.w);
  o.z = pk2(b.x, b.y); o.w = pk2(b.z, b.w);
  reinterpret_cast<uint4*>(hb)[i] = o;
}

// Pack W[64][64] f32 row-major -> A-frag order bf16:
// pw[m*4096 + ((t*2+ks)*64 + l)*8 + j] = bf16(W[ks*32 + (l>>4)*8 + j][t*16 + (l&15)])
__global__ __launch_bounds__(256) void pack_k(const float* __restrict__ W1a,
                                              const float* __restrict__ W2a,
                                              const float* __restrict__ W1b,
                                              const float* __restrict__ W2b,
                                              unsigned short* __restrict__ pw) {
  const int t = threadIdx.x;
  const float* Ws[4] = {W1a, W2a, W1b, W2b};
#pragma unroll
  for (int m = 0; m < 4; ++m) {
    const float* __restrict__ W = Ws[m];
#pragma unroll 1
    for (int i = 0; i < 16; ++i) {
      const int e = i * 256 + t;           // 0..4095
      const int j = e & 7;
      const int lv = (e >> 3) & 63;
      const int ks = (e >> 9) & 1;
      const int tt = e >> 10;
      const int k = ks * 32 + (lv >> 4) * 8 + j;
      const int n = tt * 16 + (lv & 15);
      pw[m * 4096 + e] = f2bf(W[k * 64 + n]);
    }
  }
}

// z[n] = hb[n] + sum_{j->n} hb[j]; writes bf16 row at zb + n*256B (first 128B of slot)
__global__ __launch_bounds__(256) void agg_k(const unsigned short* __restrict__ hb,
                                             const int* __restrict__ cnt,
                                             const int* __restrict__ bucket,
                                             char* __restrict__ zb) {
  const int l = threadIdx.x & 63;
  int n = blockIdx.x * (blockDim.x >> 6) + (threadIdx.x >> 6);
  if (n >= NN) return;
  n = __builtin_amdgcn_readfirstlane(n);
  const int deg = min(cnt[n], CAP);
  const int* __restrict__ brow = bucket + n * CAP;
  float acc = bf2f(hb[(n << 6) | l]);
#pragma unroll 1
  for (int e = 0; e < deg; e += 8) {
    const int4 qa = *reinterpret_cast<const int4*>(brow + e);
    const int4 qb = *reinterpret_cast<const int4*>(brow + e + 4);
    const int s0 = qa.x;
    const int s1 = (e + 1 < deg) ? qa.y : s0;
    const int s2 = (e + 2 < deg) ? qa.z : s0;
    const int s3 = (e + 3 < deg) ? qa.w : s0;
    const int s4 = (e + 4 < deg) ? qb.x : s0;
    const int s5 = (e + 5 < deg) ? qb.y : s0;
    const int s6 = (e + 6 < deg) ? qb.z : s0;
    const int s7 = (e + 7 < deg) ? qb.w : s0;
    const float v0 = bf2f(hb[(s0 << 6) | l]);
    const float v1 = bf2f(hb[(s1 << 6) | l]);
    const float v2 = bf2f(hb[(s2 << 6) | l]);
    const float v3 = bf2f(hb[(s3 << 6) | l]);
    const float v4 = bf2f(hb[(s4 << 6) | l]);
    const float v5 = bf2f(hb[(s5 << 6) | l]);
    const float v6 = bf2f(hb[(s6 << 6) | l]);
    const float v7 = bf2f(hb[(s7 << 6) | l]);
    const float w1 = (e + 1 < deg) ? v1 : 0.f;
    const float w2 = (e + 2 < deg) ? v2 : 0.f;
    const float w3 = (e + 3 < deg) ? v3 : 0.f;
    const float w4 = (e + 4 < deg) ? v4 : 0.f;
    const float w5 = (e + 5 < deg) ? v5 : 0.f;
    const float w6 = (e + 6 < deg) ? v6 : 0.f;
    const float w7 = (e + 7 < deg) ? v7 : 0.f;
    acc += ((v0 + w1) + (w2 + w3)) + ((w4 + w5) + (w6 + w7));
  }
  *reinterpret_cast<unsigned short*>(zb + n * 256 + l * 2) = f2bf(acc);
}

// Overflow edges (deg > CAP, ~never): CAS-add bf16 halves in zb rows.
__global__ __launch_bounds__(256) void ovf_fix_k(const unsigned short* __restrict__ hb,
                                                 char* __restrict__ zb,
                                                 const int* __restrict__ ovfCnt,
                                                 const int* __restrict__ ovf) {
  const int cv = min(ovfCnt[0], OVF_CAPN);
  const int l = threadIdx.x & 63;
  const int w = threadIdx.x >> 6;
  for (int p = w; p < cv; p += 4) {
    const int d = ovf[2 * p];
    const int s = ovf[2 * p + 1];
    const float add = bf2f(hb[(s << 6) | l]);
    unsigned* wp = reinterpret_cast<unsigned*>(zb + d * 256 + (l >> 1) * 4);
    const bool hi = l & 1;
    unsigned cur = atomicAdd(wp, 0u);  // load
    while (true) {
      const unsigned short hv = hi ? (unsigned short)(cur >> 16) : (unsigned short)(cur & 0xffffu);
      const unsigned short nh = f2bf(bf2f(hv) + add);
      const unsigned nw = hi ? ((cur & 0x0000ffffu) | ((unsigned)nh << 16))
                             : ((cur & 0xffff0000u) | (unsigned)nh);
      const unsigned prev = atomicCAS(wp, cur, nw);
      if (prev == cur) break;
      cur = prev;
    }
  }
}

// MFMA MLP (transposed): per 128-node tile, D1^T = W1^T @ Z^T; relu; D2^T = W2^T @ C1^T.
// 4 waves/block, wave owns 32 nodes (2 node-tiles of 16).
// LDS hand-off: unsigned-only scalar accesses, stride 33 words/row (bank=row+col: conflict-free),
// with __syncthreads() between write and read. Epilogues write directly from fragments.
template <int OUTBF>
__global__ __launch_bounds__(256) void mlp_mfma_k(
    const char* __restrict__ zb,        // bf16 z rows, stride 256B
    void* __restrict__ hout,
    const unsigned short* __restrict__ pw1, const float* __restrict__ b1,
    const unsigned short* __restrict__ pw2, const float* __restrict__ b2,
    const float* __restrict__ mask) {
  __shared__ unsigned ldsu[128 * 33];   // 16.9 KB
  const int tid = threadIdx.x;
  const int w = tid >> 6, l = tid & 63, g = l >> 4, mi = l & 15;
  const int m0 = blockIdx.x * 128;
  const int rbase = w * 32;

  // ---- Z^T B-fragments: lane holds z[node(mi)][k = ks*32 + g*8 + j] ----
  s8v zf[2][2];
#pragma unroll
  for (int tm = 0; tm < 2; ++tm) {
    const int node = m0 + rbase + tm * 16 + mi;
    const int nc = node < NN ? node : NN - 1;
#pragma unroll
    for (int ks = 0; ks < 2; ++ks)
      zf[tm][ks] = *reinterpret_cast<const s8v*>(zb + nc * 256 + (ks * 32 + g * 8) * 2);
  }

  // ---- GEMM1 (C-in = bias): D[feat=t*16+g*4+reg][node=mi] ----
  f4v acc[4][2];
#pragma unroll
  for (int t = 0; t < 4; ++t) {
    const f4v bv = *reinterpret_cast<const f4v*>(b1 + t * 16 + g * 4);
    acc[t][0] = bv; acc[t][1] = bv;
  }
#pragma unroll
  for (int t = 0; t < 4; ++t) {
#pragma unroll
    for (int ks = 0; ks < 2; ++ks) {
      const s8v wf = *reinterpret_cast<const s8v*>(pw1 + ((t * 2 + ks) * 64 + l) * 8);
#pragma unroll
      for (int tm = 0; tm < 2; ++tm)
        acc[t][tm] = __builtin_amdgcn_mfma_f32_16x16x32_bf16(wf, zf[tm][ks], acc[t][tm], 0, 0, 0);
    }
  }

  // ---- relu + pack -> LDS (unsigned scalar stores; row stride 33 words) ----
#pragma unroll
  for (int t = 0; t < 4; ++t) {
#pragma unroll
    for (int tm = 0; tm < 2; ++tm) {
      const f4v a = acc[t][tm];
      const int row = rbase + tm * 16 + mi;
      const int base = row * 33 + t * 8 + g * 2;   // feature f stored at word f/2
      ldsu[base]     = pk2(fmaxf(a.x, 0.f), fmaxf(a.y, 0.f));
      ldsu[base + 1] = pk2(fmaxf(a.z, 0.f), fmaxf(a.w, 0.f));
    }
  }
  __syncthreads();

  // ---- GEMM2 B-fragments: lane needs c1[node(mi)][k = ks*32 + g*8 + j] ----
  s8v cf[2][2];
#pragma unroll
  for (int tm = 0; tm < 2; ++tm) {
    const int row = rbase + tm * 16 + mi;
    const int cbase = row * 33 + (mi < 0 ? 0 : 0);  // keep simple: computed below
#pragma unroll
    for (int ks = 0; ks < 2; ++ks) {
      const int b0 = row * 33 + ks * 16 + g * 4;
      U8 u8;
      u8.u[0] = ldsu[b0 + 0];
      u8.u[1] = ldsu[b0 + 1];
      u8.u[2] = ldsu[b0 + 2];
      u8.u[3] = ldsu[b0 + 3];
      cf[tm][ks] = u8.s;
    }
    (void)cbase;
  }

  f4v acc2[4][2];
#pragma unroll
  for (int t = 0; t < 4; ++t) {
    const f4v bv = *reinterpret_cast<const f4v*>(b2 + t * 16 + g * 4);
    acc2[t][0] = bv; acc2[t][1] = bv;
  }
#pragma unroll
  for (int t = 0; t < 4; ++t) {
#pragma unroll
    for (int ks = 0; ks < 2; ++ks) {
      const s8v wf = *reinterpret_cast<const s8v*>(pw2 + ((t * 2 + ks) * 64 + l) * 8);
#pragma unroll
      for (int tm = 0; tm < 2; ++tm)
        acc2[t][tm] = __builtin_amdgcn_mfma_f32_16x16x32_bf16(wf, cf[tm][ks], acc2[t][tm], 0, 0, 0);
    }
  }

  // ---- epilogue: direct fragment stores ----
  if (OUTBF) {
    unsigned* __restrict__ ho = reinterpret_cast<unsigned*>(hout);
#pragma unroll
    for (int tm = 0; tm < 2; ++tm) {
      const int node = m0 + rbase + tm * 16 + mi;
      if (node < NN) {
#pragma unroll
        for (int t = 0; t < 4; ++t) {
          const f4v a = acc2[t][tm];
          const int idx = node * 32 + t * 8 + g * 2;  // 128B rows = 32 words
          uint2 p;
          p.x = pk2(a.x, a.y);
          p.y = pk2(a.z, a.w);
          *reinterpret_cast<uint2*>(&ho[idx]) = p;
        }
      }
    }
  } else {
    float* __restrict__ fo = reinterpret_cast<float*>(hout);
#pragma unroll
    for (int tm = 0; tm < 2; ++tm) {
      const int node = m0 + rbase + tm * 16 + mi;
      if (node < NN) {
        const float mv = mask[node];
#pragma unroll
        for (int t = 0; t < 4; ++t) {
          f4v v = acc2[t][tm];
          v *= mv;
          *reinterpret_cast<f4v*>(fo + node * 64 + t * 16 + g * 4) = v;
        }
      }
    }
  }
}

__global__ __launch_bounds__(256) void xcopy_k(const float* __restrict__ x,
                                               float* __restrict__ ox) {
  const int i = blockIdx.x * blockDim.x + threadIdx.x;
  if (i < (NN * 3) / 4) {
    reinterpret_cast<float4*>(ox)[i] = reinterpret_cast<const float4*>(x)[i];
  }
}

extern "C" void kernel_launch(void* const* d_in, const int* in_sizes, int n_in,
                              void* d_out, int out_size, void* d_ws, size_t ws_size,
                              hipStream_t stream) {
  (void)in_sizes; (void)n_in; (void)out_size; (void)ws_size;
  const float* h    = (const float*)d_in[0];
  const float* x    = (const float*)d_in[1];
  const int*   ei   = (const int*)d_in[2];
  const float* mask = (const float*)d_in[3];
  const float* W1_0 = (const float*)d_in[4];
  const float* b1_0 = (const float*)d_in[5];
  const float* W2_0 = (const float*)d_in[6];
  const float* b2_0 = (const float*)d_in[7];
  const float* W1_1 = (const float*)d_in[8];
  const float* b1_1 = (const float*)d_in[9];
  const float* W2_1 = (const float*)d_in[10];
  const float* b2_1 = (const float*)d_in[11];
  float* out = (float*)d_out;

  const int* src = ei;       // edge_index[0]
  const int* dst = ei + EE;  // edge_index[1]

  int* wsp       = (int*)d_ws;
  int* binTot    = wsp;
  int* ovfCnt    = wsp + OVFC_OFF;
  int* ovf       = wsp + OVF_OFF;
  int* binStart  = wsp + BSTART_OFF;
  int* cursor    = wsp + CURSOR_OFF;
  int* cnt       = wsp + CNT_OFF;
  int* bucket    = wsp + BUCK_OFF;
  int* binned    = wsp + BINNED_OFF;
  unsigned* hb   = (unsigned*)(wsp + HB_OFF);      // bf16 h, later bf16 h1
  unsigned short* pw = (unsigned short*)(wsp + PW_OFF);
  const unsigned short* hbs = (const unsigned short*)hb;
  char* zb       = (char*)d_out;  // bf16 z rows at node*256B (block-local in-place for mlp2)

  // --- edge structure build (once, reused by both layers) ---
  hipMemsetAsync(d_ws, 0, 8192, stream);  // binTot + ovfCnt
  hist_k<<<256, 256, 0, stream>>>(dst, binTot);
  scan_k<<<1, 1024, 0, stream>>>(binTot, binStart, cursor);
  scatter_k<<<256, 256, 0, stream>>>(src, dst, cursor, binned);
  bucketize_k<<<782, 256, 0, stream>>>(binStart, binned, bucket, cnt, ovf);

  // --- weight packing (independent) ---
  pack_k<<<1, 256, 0, stream>>>(W1_0, W2_0, W1_1, W2_1, pw);

  // --- layer 1 ---
  cvt_k<<<3125, 256, 0, stream>>>(h, hb);  // binned dead; region becomes hb
  agg_k<<<25000, 256, 0, stream>>>(hbs, cnt, bucket, zb);
  ovf_fix_k<<<1, 256, 0, stream>>>(hbs, zb, ovfCnt, ovf);
  mlp_mfma_k<1><<<782, 256, 0, stream>>>(zb, hb, pw, b1_0, pw + 4096, b2_0, nullptr);

  // --- layer 2 ---
  agg_k<<<25000, 256, 0, stream>>>(hbs, cnt, bucket, zb);
  ovf_fix_k<<<1, 256, 0, stream>>>(hbs, zb, ovfCnt, ovf);
  mlp_mfma_k<0><<<782, 256, 0, stream>>>(zb, out, pw + 8192, b1_1, pw + 12288, b2_1, mask);

  // --- x passthrough ---
  xcopy_k<<<293, 256, 0, stream>>>(x, out + NN * 64);
}

// Round 8
// 167.484 us; speedup vs baseline: 1.7713x; 1.0634x over previous
//
#include <hip/hip_runtime.h>

// GIN block, 2 layers: h = mlp(h + segsum(h[src], dst)); out = (h*mask, x)
// N=100000, E=1600000, D=64.
// Round-8 (from verified round-7):
//  - agg restructured: lane = (slot s = l>>4, feat-group g = l&15); each lane loads uint2
//    (8B = 4 feats) so ONE instruction gathers 4 rows; 8 insts = 32 edges in flight;
//    cross-slot shfl_xor reduce. ~4x fewer issue slots per gathered byte.
//  - setup_k = weight pack + zero binTot/ovfCnt (kills hipMemsetAsync dispatch)
//  - cvtx_k = cvt + x-passthrough in one dispatch
//  - int2-vectorized dst/src reads in hist/scatter
//  - mlp_mfma / scan / bucketize / ovf_fix unchanged (verified in round 7)

#define NN 100000
#define EE 1600000
#define CAP 48
#define NBIN 1024
#define CHB 6250
#define OVF_CAPN 8000

// ws layout (ints):
//   binTot   @ 0        (1024)   -- zeroed by setup_k
//   ovfCnt   @ 1024     (1)      -- zeroed by setup_k
//   ovf      @ 1026     (2*8000)
//   binStart @ 17056    (1025)
//   cursor   @ 18112    (1024)
//   cnt      @ 19200    (100000)
//   bucket   @ 119296   (NN*CAP)
//   binned   @ 4919296  (EE)       } binned dead after bucketize ->
//   hb/hb1   @ 4919296  (3200000)  } region becomes bf16 h / bf16 h1
//   pw       @ 8119296  (16384 shorts)
#define OVFC_OFF   1024
#define OVF_OFF    1026
#define BSTART_OFF 17056
#define CURSOR_OFF 18112
#define CNT_OFF    19200
#define BUCK_OFF   119296
#define BINNED_OFF 4919296
#define HB_OFF     4919296
#define PW_OFF     8119296

typedef __attribute__((ext_vector_type(8))) short s8v;
typedef __attribute__((ext_vector_type(4))) float f4v;

union U8 { unsigned u[4]; s8v s; };

static __device__ __forceinline__ unsigned short f2bf(float f) {
  unsigned u = __float_as_uint(f);
  return (unsigned short)((u + 0x7FFF + ((u >> 16) & 1)) >> 16);  // RTNE
}
static __device__ __forceinline__ float bf2f(unsigned short s) {
  return __uint_as_float(((unsigned)s) << 16);
}
static __device__ __forceinline__ unsigned pk2(float lo, float hi) {
  return (unsigned)f2bf(lo) | ((unsigned)f2bf(hi) << 16);
}

// setup: zero binTot+ovfCnt, pack W[64][64] f32 row-major -> A-frag order bf16:
// pw[m*4096 + ((t*2+ks)*64 + l)*8 + j] = bf16(W[ks*32 + (l>>4)*8 + j][t*16 + (l&15)])
__global__ __launch_bounds__(256) void setup_k(const float* __restrict__ W1a,
                                               const float* __restrict__ W2a,
                                               const float* __restrict__ W1b,
                                               const float* __restrict__ W2b,
                                               unsigned short* __restrict__ pw,
                                               int* __restrict__ wsp) {
  const int t = threadIdx.x;
#pragma unroll
  for (int i = t; i < 2048; i += 256) wsp[i] = 0;   // binTot + ovfCnt (+ harmless ovf head)
  const float* Ws[4] = {W1a, W2a, W1b, W2b};
#pragma unroll
  for (int m = 0; m < 4; ++m) {
    const float* __restrict__ W = Ws[m];
#pragma unroll 1
    for (int i = 0; i < 16; ++i) {
      const int e = i * 256 + t;           // 0..4095
      const int j = e & 7;
      const int lv = (e >> 3) & 63;
      const int ks = (e >> 9) & 1;
      const int tt = e >> 10;
      const int k = ks * 32 + (lv >> 4) * 8 + j;
      const int n = tt * 16 + (lv & 15);
      pw[m * 4096 + e] = f2bf(W[k * 64 + n]);
    }
  }
}

__global__ __launch_bounds__(256) void hist_k(const int* __restrict__ dst,
                                              int* __restrict__ binTot) {
  __shared__ int hist[NBIN];
  const int t = threadIdx.x;
#pragma unroll
  for (int b = t; b < NBIN; b += 256) hist[b] = 0;
  __syncthreads();
  const int s = blockIdx.x * CHB;
#pragma unroll 1
  for (int p = t; p < CHB / 2; p += 256) {
    const int2 dd = *reinterpret_cast<const int2*>(dst + s + 2 * p);
    atomicAdd(&hist[dd.x >> 7], 1);
    atomicAdd(&hist[dd.y >> 7], 1);
  }
  __syncthreads();
#pragma unroll
  for (int b = t; b < NBIN; b += 256) {
    const int c = hist[b];
    if (c) atomicAdd(&binTot[b], c);
  }
}

__global__ __launch_bounds__(1024) void scan_k(const int* __restrict__ binTot,
                                               int* __restrict__ binStart,
                                               int* __restrict__ cursor) {
  __shared__ int sh[NBIN];
  const int t = threadIdx.x;
  const int v = binTot[t];
  sh[t] = v;
  __syncthreads();
  for (int off = 1; off < NBIN; off <<= 1) {
    const int x = (t >= off) ? sh[t - off] : 0;
    __syncthreads();
    sh[t] += x;
    __syncthreads();
  }
  binStart[t] = sh[t] - v;
  cursor[t] = sh[t] - v;
  if (t == NBIN - 1) binStart[NBIN] = sh[t];
}

__global__ __launch_bounds__(256) void scatter_k(const int* __restrict__ src,
                                                 const int* __restrict__ dst,
                                                 int* __restrict__ cursor,
                                                 int* __restrict__ binned) {
  __shared__ int hist[NBIN], base[NBIN], lcnt[NBIN];
  const int t = threadIdx.x;
#pragma unroll
  for (int b = t; b < NBIN; b += 256) { hist[b] = 0; lcnt[b] = 0; }
  __syncthreads();
  const int s = blockIdx.x * CHB;
#pragma unroll 1
  for (int p = t; p < CHB / 2; p += 256) {
    const int2 dd = *reinterpret_cast<const int2*>(dst + s + 2 * p);
    atomicAdd(&hist[dd.x >> 7], 1);
    atomicAdd(&hist[dd.y >> 7], 1);
  }
  __syncthreads();
#pragma unroll
  for (int b = t; b < NBIN; b += 256) {
    const int c = hist[b];
    base[b] = c ? atomicAdd(&cursor[b], c) : 0;
  }
  __syncthreads();
#pragma unroll 1
  for (int p = t; p < CHB / 2; p += 256) {
    const int i = s + 2 * p;
    const int2 dd = *reinterpret_cast<const int2*>(dst + i);
    const int2 ss = *reinterpret_cast<const int2*>(src + i);
    int bin = dd.x >> 7;
    int off = atomicAdd(&lcnt[bin], 1);
    binned[base[bin] + off] = ((dd.x & 127) << 17) | ss.x;
    bin = dd.y >> 7;
    off = atomicAdd(&lcnt[bin], 1);
    binned[base[bin] + off] = ((dd.y & 127) << 17) | ss.y;
  }
}

__global__ __launch_bounds__(256) void bucketize_k(const int* __restrict__ binStart,
                                                   const int* __restrict__ binned,
                                                   int* __restrict__ bucket,
                                                   int* __restrict__ cnt,
                                                   int* __restrict__ ovf) {
  __shared__ int c128[128];
  const int t = threadIdx.x;
  const int bin = blockIdx.x;
  const int nbase = bin << 7;
  if (t < 128) c128[t] = 0;
  __syncthreads();
  const int s0 = binStart[bin], s1 = binStart[bin + 1];
#pragma unroll 1
  for (int i = s0 + t; i < s1; i += 256) {
    const int p = binned[i];
    const int dlow = p >> 17;
    const int sv = p & 131071;
    const int slot = atomicAdd(&c128[dlow], 1);
    if (slot < CAP) {
      bucket[(nbase + dlow) * CAP + slot] = sv;
    } else {
      const int q = atomicAdd(&ovf[-2], 1);  // ovf[-2] == ovfCnt
      if (q < OVF_CAPN) { ovf[2 * q] = nbase + dlow; ovf[2 * q + 1] = sv; }
    }
  }
  __syncthreads();
  if (t < 128 && nbase + t < NN) cnt[nbase + t] = c128[t];
}

// cvt (h f32 -> hb bf16 rows) + x passthrough, one dispatch
__global__ __launch_bounds__(256) void cvtx_k(const float* __restrict__ h,
                                              unsigned* __restrict__ hb,
                                              const float* __restrict__ x,
                                              float* __restrict__ ox) {
  const int b = blockIdx.x;
  const int t = threadIdx.x;
  if (b < 3125) {
    const int i = b * 256 + t;             // 0..799999
    const float4* __restrict__ h4 = reinterpret_cast<const float4*>(h);
    const float4 a = h4[2 * i], c = h4[2 * i + 1];
    uint4 o;
    o.x = pk2(a.x, a.y); o.y = pk2(a.z, a.w);
    o.z = pk2(c.x, c.y); o.w = pk2(c.z, c.w);
    reinterpret_cast<uint4*>(hb)[i] = o;
  } else {
    const int i = (b - 3125) * 256 + t;
    if (i < (NN * 3) / 4)
      reinterpret_cast<float4*>(ox)[i] = reinterpret_cast<const float4*>(x)[i];
  }
}

// z[n] = hb[n] + sum_{j->n} hb[j].
// Wave per node; lane = (slot s = l>>4, group g = l&15). Lane loads uint2 (feats 4g..4g+3)
// of row (it*32 + s*8 + d); 8 insts cover 32 rows; shfl_xor(16,32) reduces slots.
__global__ __launch_bounds__(256) void agg_k(const unsigned short* __restrict__ hb,
                                             const int* __restrict__ cnt,
                                             const int* __restrict__ bucket,
                                             unsigned* __restrict__ zbu) {
  const int l = threadIdx.x & 63;
  const int s = l >> 4, g = l & 15;
  int n = blockIdx.x * 4 + (threadIdx.x >> 6);
  n = __builtin_amdgcn_readfirstlane(n);
  if (n >= NN) return;
  const int deg = min(cnt[n], CAP);
  const int* __restrict__ brow = bucket + n * CAP;
  const uint2* __restrict__ h2 = reinterpret_cast<const uint2*>(hb);

  // self row: only slot 0 seeds it (others contribute 0)
  const uint2 sv = h2[n * 16 + g];
  const unsigned m0 = (s == 0) ? sv.x : 0u;
  const unsigned m1 = (s == 0) ? sv.y : 0u;
  float a0 = __uint_as_float(m0 << 16);
  float a1 = __uint_as_float(m0 & 0xffff0000u);
  float a2 = __uint_as_float(m1 << 16);
  float a3 = __uint_as_float(m1 & 0xffff0000u);

#pragma unroll 1
  for (int it = 0; it * 32 < deg; ++it) {
    const int base = it * 32 + s * 8;      // this slot's 8 rows
    const int4 qa = *reinterpret_cast<const int4*>(brow + base);
    const int4 qb = *reinterpret_cast<const int4*>(brow + base + 4);
    const bool k0 = base + 0 < deg, k1 = base + 1 < deg, k2 = base + 2 < deg, k3 = base + 3 < deg;
    const bool k4 = base + 4 < deg, k5 = base + 5 < deg, k6 = base + 6 < deg, k7 = base + 7 < deg;
    const int i0 = k0 ? qa.x : n, i1 = k1 ? qa.y : n, i2 = k2 ? qa.z : n, i3 = k3 ? qa.w : n;
    const int i4 = k4 ? qb.x : n, i5 = k5 ? qb.y : n, i6 = k6 ? qb.z : n, i7 = k7 ? qb.w : n;
    const uint2 v0 = h2[i0 * 16 + g];
    const uint2 v1 = h2[i1 * 16 + g];
    const uint2 v2 = h2[i2 * 16 + g];
    const uint2 v3 = h2[i3 * 16 + g];
    const uint2 v4 = h2[i4 * 16 + g];
    const uint2 v5 = h2[i5 * 16 + g];
    const uint2 v6 = h2[i6 * 16 + g];
    const uint2 v7 = h2[i7 * 16 + g];
#define ACC(vv, kk)                                                      \
    { const unsigned ux = kk ? vv.x : 0u, uy = kk ? vv.y : 0u;           \
      a0 += __uint_as_float(ux << 16);                                   \
      a1 += __uint_as_float(ux & 0xffff0000u);                           \
      a2 += __uint_as_float(uy << 16);                                   \
      a3 += __uint_as_float(uy & 0xffff0000u); }
    ACC(v0, k0) ACC(v1, k1) ACC(v2, k2) ACC(v3, k3)
    ACC(v4, k4) ACC(v5, k5) ACC(v6, k6) ACC(v7, k7)
#undef ACC
  }

  // reduce over slots (lane ^16, ^32)
  a0 += __shfl_xor(a0, 16); a1 += __shfl_xor(a1, 16);
  a2 += __shfl_xor(a2, 16); a3 += __shfl_xor(a3, 16);
  a0 += __shfl_xor(a0, 32); a1 += __shfl_xor(a1, 32);
  a2 += __shfl_xor(a2, 32); a3 += __shfl_xor(a3, 32);

  if (s == 0) {
    uint2 o;
    o.x = pk2(a0, a1);
    o.y = pk2(a2, a3);
    reinterpret_cast<uint2*>(zbu)[n * 32 + g] = o;   // zb row: 256B, bf16 in first 128B
  }
}

// Overflow edges (deg > CAP, ~never): CAS-add bf16 halves in zb rows.
__global__ __launch_bounds__(256) void ovf_fix_k(const unsigned short* __restrict__ hb,
                                                 char* __restrict__ zb,
                                                 const int* __restrict__ ovfCnt,
                                                 const int* __restrict__ ovf) {
  const int cv = min(ovfCnt[0], OVF_CAPN);
  const int l = threadIdx.x & 63;
  const int w = threadIdx.x >> 6;
  for (int p = w; p < cv; p += 4) {
    const int d = ovf[2 * p];
    const int s = ovf[2 * p + 1];
    const float add = bf2f(hb[(s << 6) | l]);
    unsigned* wp = reinterpret_cast<unsigned*>(zb + d * 256 + (l >> 1) * 4);
    const bool hi = l & 1;
    unsigned cur = atomicAdd(wp, 0u);  // load
    while (true) {
      const unsigned short hv = hi ? (unsigned short)(cur >> 16) : (unsigned short)(cur & 0xffffu);
      const unsigned short nh = f2bf(bf2f(hv) + add);
      const unsigned nw = hi ? ((cur & 0x0000ffffu) | ((unsigned)nh << 16))
                             : ((cur & 0xffff0000u) | (unsigned)nh);
      const unsigned prev = atomicCAS(wp, cur, nw);
      if (prev == cur) break;
      cur = prev;
    }
  }
}

// MFMA MLP (verified round 7): per 128-node tile, D1^T = W1^T @ Z^T; relu; D2^T = W2^T @ C1^T.
template <int OUTBF>
__global__ __launch_bounds__(256) void mlp_mfma_k(
    const char* __restrict__ zb,        // bf16 z rows, stride 256B
    void* __restrict__ hout,
    const unsigned short* __restrict__ pw1, const float* __restrict__ b1,
    const unsigned short* __restrict__ pw2, const float* __restrict__ b2,
    const float* __restrict__ mask) {
  __shared__ unsigned ldsu[128 * 33];   // 16.9 KB
  const int tid = threadIdx.x;
  const int w = tid >> 6, l = tid & 63, g = l >> 4, mi = l & 15;
  const int m0 = blockIdx.x * 128;
  const int rbase = w * 32;

  // Z^T B-fragments: lane holds z[node(mi)][k = ks*32 + g*8 + j]
  s8v zf[2][2];
#pragma unroll
  for (int tm = 0; tm < 2; ++tm) {
    const int node = m0 + rbase + tm * 16 + mi;
    const int nc = node < NN ? node : NN - 1;
#pragma unroll
    for (int ks = 0; ks < 2; ++ks)
      zf[tm][ks] = *reinterpret_cast<const s8v*>(zb + nc * 256 + (ks * 32 + g * 8) * 2);
  }

  // GEMM1 (C-in = bias)
  f4v acc[4][2];
#pragma unroll
  for (int t = 0; t < 4; ++t) {
    const f4v bv = *reinterpret_cast<const f4v*>(b1 + t * 16 + g * 4);
    acc[t][0] = bv; acc[t][1] = bv;
  }
#pragma unroll
  for (int t = 0; t < 4; ++t) {
#pragma unroll
    for (int ks = 0; ks < 2; ++ks) {
      const s8v wf = *reinterpret_cast<const s8v*>(pw1 + ((t * 2 + ks) * 64 + l) * 8);
#pragma unroll
      for (int tm = 0; tm < 2; ++tm)
        acc[t][tm] = __builtin_amdgcn_mfma_f32_16x16x32_bf16(wf, zf[tm][ks], acc[t][tm], 0, 0, 0);
    }
  }

  // relu + pack -> LDS (unsigned scalar stores; row stride 33 words)
#pragma unroll
  for (int t = 0; t < 4; ++t) {
#pragma unroll
    for (int tm = 0; tm < 2; ++tm) {
      const f4v a = acc[t][tm];
      const int row = rbase + tm * 16 + mi;
      const int base = row * 33 + t * 8 + g * 2;
      ldsu[base]     = pk2(fmaxf(a.x, 0.f), fmaxf(a.y, 0.f));
      ldsu[base + 1] = pk2(fmaxf(a.z, 0.f), fmaxf(a.w, 0.f));
    }
  }
  __syncthreads();

  // GEMM2 B-fragments from LDS
  s8v cf[2][2];
#pragma unroll
  for (int tm = 0; tm < 2; ++tm) {
    const int row = rbase + tm * 16 + mi;
#pragma unroll
    for (int ks = 0; ks < 2; ++ks) {
      const int b0 = row * 33 + ks * 16 + g * 4;
      U8 u8;
      u8.u[0] = ldsu[b0 + 0];
      u8.u[1] = ldsu[b0 + 1];
      u8.u[2] = ldsu[b0 + 2];
      u8.u[3] = ldsu[b0 + 3];
      cf[tm][ks] = u8.s;
    }
  }

  f4v acc2[4][2];
#pragma unroll
  for (int t = 0; t < 4; ++t) {
    const f4v bv = *reinterpret_cast<const f4v*>(b2 + t * 16 + g * 4);
    acc2[t][0] = bv; acc2[t][1] = bv;
  }
#pragma unroll
  for (int t = 0; t < 4; ++t) {
#pragma unroll
    for (int ks = 0; ks < 2; ++ks) {
      const s8v wf = *reinterpret_cast<const s8v*>(pw2 + ((t * 2 + ks) * 64 + l) * 8);
#pragma unroll
      for (int tm = 0; tm < 2; ++tm)
        acc2[t][tm] = __builtin_amdgcn_mfma_f32_16x16x32_bf16(wf, cf[tm][ks], acc2[t][tm], 0, 0, 0);
    }
  }

  // epilogue: direct fragment stores
  if (OUTBF) {
    unsigned* __restrict__ ho = reinterpret_cast<unsigned*>(hout);
#pragma unroll
    for (int tm = 0; tm < 2; ++tm) {
      const int node = m0 + rbase + tm * 16 + mi;
      if (node < NN) {
#pragma unroll
        for (int t = 0; t < 4; ++t) {
          const f4v a = acc2[t][tm];
          const int idx = node * 32 + t * 8 + g * 2;
          uint2 p;
          p.x = pk2(a.x, a.y);
          p.y = pk2(a.z, a.w);
          *reinterpret_cast<uint2*>(&ho[idx]) = p;
        }
      }
    }
  } else {
    float* __restrict__ fo = reinterpret_cast<float*>(hout);
#pragma unroll
    for (int tm = 0; tm < 2; ++tm) {
      const int node = m0 + rbase + tm * 16 + mi;
      if (node < NN) {
        const float mv = mask[node];
#pragma unroll
        for (int t = 0; t < 4; ++t) {
          f4v v = acc2[t][tm];
          v *= mv;
          *reinterpret_cast<f4v*>(fo + node * 64 + t * 16 + g * 4) = v;
        }
      }
    }
  }
}

extern "C" void kernel_launch(void* const* d_in, const int* in_sizes, int n_in,
                              void* d_out, int out_size, void* d_ws, size_t ws_size,
                              hipStream_t stream) {
  (void)in_sizes; (void)n_in; (void)out_size; (void)ws_size;
  const float* h    = (const float*)d_in[0];
  const float* x    = (const float*)d_in[1];
  const int*   ei   = (const int*)d_in[2];
  const float* mask = (const float*)d_in[3];
  const float* W1_0 = (const float*)d_in[4];
  const float* b1_0 = (const float*)d_in[5];
  const float* W2_0 = (const float*)d_in[6];
  const float* b2_0 = (const float*)d_in[7];
  const float* W1_1 = (const float*)d_in[8];
  const float* b1_1 = (const float*)d_in[9];
  const float* W2_1 = (const float*)d_in[10];
  const float* b2_1 = (const float*)d_in[11];
  float* out = (float*)d_out;

  const int* src = ei;       // edge_index[0]
  const int* dst = ei + EE;  // edge_index[1]

  int* wsp       = (int*)d_ws;
  int* binTot    = wsp;
  int* ovfCnt    = wsp + OVFC_OFF;
  int* ovf       = wsp + OVF_OFF;
  int* binStart  = wsp + BSTART_OFF;
  int* cursor    = wsp + CURSOR_OFF;
  int* cnt       = wsp + CNT_OFF;
  int* bucket    = wsp + BUCK_OFF;
  int* binned    = wsp + BINNED_OFF;
  unsigned* hb   = (unsigned*)(wsp + HB_OFF);      // bf16 h, later bf16 h1
  unsigned short* pw = (unsigned short*)(wsp + PW_OFF);
  const unsigned short* hbs = (const unsigned short*)hb;
  unsigned* zbu  = (unsigned*)d_out;  // bf16 z rows at node*256B
  char* zb       = (char*)d_out;

  // --- edge structure build (once, reused by both layers) ---
  setup_k<<<1, 256, 0, stream>>>(W1_0, W2_0, W1_1, W2_1, pw, wsp);  // zero + pack
  hist_k<<<256, 256, 0, stream>>>(dst, binTot);
  scan_k<<<1, 1024, 0, stream>>>(binTot, binStart, cursor);
  scatter_k<<<256, 256, 0, stream>>>(src, dst, cursor, binned);
  bucketize_k<<<782, 256, 0, stream>>>(binStart, binned, bucket, cnt, ovf);

  // --- h -> bf16 + x passthrough (binned dead; region becomes hb) ---
  cvtx_k<<<3418, 256, 0, stream>>>(h, hb, x, out + NN * 64);

  // --- layer 1 ---
  agg_k<<<25000, 256, 0, stream>>>(hbs, cnt, bucket, zbu);
  ovf_fix_k<<<1, 256, 0, stream>>>(hbs, zb, ovfCnt, ovf);
  mlp_mfma_k<1><<<782, 256, 0, stream>>>(zb, hb, pw, b1_0, pw + 4096, b2_0, nullptr);

  // --- layer 2 ---
  agg_k<<<25000, 256, 0, stream>>>(hbs, cnt, bucket, zbu);
  ovf_fix_k<<<1, 256, 0, stream>>>(hbs, zb, ovfCnt, ovf);
  mlp_mfma_k<0><<<782, 256, 0, stream>>>(zb, out, pw + 8192, b1_1, pw + 12288, b2_1, mask);
}

// Round 9
// 164.353 us; speedup vs baseline: 1.8051x; 1.0191x over previous
//
#include <hip/hip_runtime.h>

// GIN block, 2 layers: h = mlp(h + segsum(h[src], dst)); out = (h*mask, x)
// N=100000, E=1600000, D=64.
// Round-9 (from verified round-8):
//  - agg: branch-free gather. Bucket rows padded to mult-of-16 with dummy index NN;
//    hb[NN] is a 128B zero row. Batch = 16 rows (4 slots x 4 rows), one int4 index
//    load + 4 unconditional uint2 gathers per lane per iter. No masks at all.
//  - bucketize: pads slots deg..ceil(deg/16)*16 (<=CAP) with NN.
//  - cvtx: also zeroes hb[NN] row.  pw shifted +32 ints to make room.
//  - hist/scan/scatter/mlp_mfma/ovf_fix unchanged (verified round 7/8).

#define NN 100000
#define EE 1600000
#define CAP 48
#define NBIN 1024
#define CHB 6250
#define OVF_CAPN 8000

// ws layout (ints):
//   binTot   @ 0        (1024)   -- zeroed by setup_k
//   ovfCnt   @ 1024     (1)      -- zeroed by setup_k
//   ovf      @ 1026     (2*8000)
//   binStart @ 17056    (1025)
//   cursor   @ 18112    (1024)
//   cnt      @ 19200    (100000)
//   bucket   @ 119296   (NN*CAP)
//   binned   @ 4919296  (EE)          } binned dead after bucketize ->
//   hb/hb1   @ 4919296  (3200032)     } bf16 h / bf16 h1, + zero row at hb[NN]
//   pw       @ 8119328  (16384 shorts)
#define OVFC_OFF   1024
#define OVF_OFF    1026
#define BSTART_OFF 17056
#define CURSOR_OFF 18112
#define CNT_OFF    19200
#define BUCK_OFF   119296
#define BINNED_OFF 4919296
#define HB_OFF     4919296
#define PW_OFF     8119328

typedef __attribute__((ext_vector_type(8))) short s8v;
typedef __attribute__((ext_vector_type(4))) float f4v;

union U8 { unsigned u[4]; s8v s; };

static __device__ __forceinline__ unsigned short f2bf(float f) {
  unsigned u = __float_as_uint(f);
  return (unsigned short)((u + 0x7FFF + ((u >> 16) & 1)) >> 16);  // RTNE
}
static __device__ __forceinline__ float bf2f(unsigned short s) {
  return __uint_as_float(((unsigned)s) << 16);
}
static __device__ __forceinline__ unsigned pk2(float lo, float hi) {
  return (unsigned)f2bf(lo) | ((unsigned)f2bf(hi) << 16);
}

// setup: zero binTot+ovfCnt, pack W[64][64] f32 row-major -> A-frag order bf16:
// pw[m*4096 + ((t*2+ks)*64 + l)*8 + j] = bf16(W[ks*32 + (l>>4)*8 + j][t*16 + (l&15)])
__global__ __launch_bounds__(256) void setup_k(const float* __restrict__ W1a,
                                               const float* __restrict__ W2a,
                                               const float* __restrict__ W1b,
                                               const float* __restrict__ W2b,
                                               unsigned short* __restrict__ pw,
                                               int* __restrict__ wsp) {
  const int t = threadIdx.x;
#pragma unroll
  for (int i = t; i < 2048; i += 256) wsp[i] = 0;   // binTot + ovfCnt (+ harmless ovf head)
  const float* Ws[4] = {W1a, W2a, W1b, W2b};
#pragma unroll
  for (int m = 0; m < 4; ++m) {
    const float* __restrict__ W = Ws[m];
#pragma unroll 1
    for (int i = 0; i < 16; ++i) {
      const int e = i * 256 + t;           // 0..4095
      const int j = e & 7;
      const int lv = (e >> 3) & 63;
      const int ks = (e >> 9) & 1;
      const int tt = e >> 10;
      const int k = ks * 32 + (lv >> 4) * 8 + j;
      const int n = tt * 16 + (lv & 15);
      pw[m * 4096 + e] = f2bf(W[k * 64 + n]);
    }
  }
}

__global__ __launch_bounds__(256) void hist_k(const int* __restrict__ dst,
                                              int* __restrict__ binTot) {
  __shared__ int hist[NBIN];
  const int t = threadIdx.x;
#pragma unroll
  for (int b = t; b < NBIN; b += 256) hist[b] = 0;
  __syncthreads();
  const int s = blockIdx.x * CHB;
#pragma unroll 1
  for (int p = t; p < CHB / 2; p += 256) {
    const int2 dd = *reinterpret_cast<const int2*>(dst + s + 2 * p);
    atomicAdd(&hist[dd.x >> 7], 1);
    atomicAdd(&hist[dd.y >> 7], 1);
  }
  __syncthreads();
#pragma unroll
  for (int b = t; b < NBIN; b += 256) {
    const int c = hist[b];
    if (c) atomicAdd(&binTot[b], c);
  }
}

__global__ __launch_bounds__(1024) void scan_k(const int* __restrict__ binTot,
                                               int* __restrict__ binStart,
                                               int* __restrict__ cursor) {
  __shared__ int sh[NBIN];
  const int t = threadIdx.x;
  const int v = binTot[t];
  sh[t] = v;
  __syncthreads();
  for (int off = 1; off < NBIN; off <<= 1) {
    const int x = (t >= off) ? sh[t - off] : 0;
    __syncthreads();
    sh[t] += x;
    __syncthreads();
  }
  binStart[t] = sh[t] - v;
  cursor[t] = sh[t] - v;
  if (t == NBIN - 1) binStart[NBIN] = sh[t];
}

__global__ __launch_bounds__(256) void scatter_k(const int* __restrict__ src,
                                                 const int* __restrict__ dst,
                                                 int* __restrict__ cursor,
                                                 int* __restrict__ binned) {
  __shared__ int hist[NBIN], base[NBIN], lcnt[NBIN];
  const int t = threadIdx.x;
#pragma unroll
  for (int b = t; b < NBIN; b += 256) { hist[b] = 0; lcnt[b] = 0; }
  __syncthreads();
  const int s = blockIdx.x * CHB;
#pragma unroll 1
  for (int p = t; p < CHB / 2; p += 256) {
    const int2 dd = *reinterpret_cast<const int2*>(dst + s + 2 * p);
    atomicAdd(&hist[dd.x >> 7], 1);
    atomicAdd(&hist[dd.y >> 7], 1);
  }
  __syncthreads();
#pragma unroll
  for (int b = t; b < NBIN; b += 256) {
    const int c = hist[b];
    base[b] = c ? atomicAdd(&cursor[b], c) : 0;
  }
  __syncthreads();
#pragma unroll 1
  for (int p = t; p < CHB / 2; p += 256) {
    const int i = s + 2 * p;
    const int2 dd = *reinterpret_cast<const int2*>(dst + i);
    const int2 ss = *reinterpret_cast<const int2*>(src + i);
    int bin = dd.x >> 7;
    int off = atomicAdd(&lcnt[bin], 1);
    binned[base[bin] + off] = ((dd.x & 127) << 17) | ss.x;
    bin = dd.y >> 7;
    off = atomicAdd(&lcnt[bin], 1);
    binned[base[bin] + off] = ((dd.y & 127) << 17) | ss.y;
  }
}

__global__ __launch_bounds__(256) void bucketize_k(const int* __restrict__ binStart,
                                                   const int* __restrict__ binned,
                                                   int* __restrict__ bucket,
                                                   int* __restrict__ cnt,
                                                   int* __restrict__ ovf) {
  __shared__ int c128[128];
  const int t = threadIdx.x;
  const int bin = blockIdx.x;
  const int nbase = bin << 7;
  if (t < 128) c128[t] = 0;
  __syncthreads();
  const int s0 = binStart[bin], s1 = binStart[bin + 1];
#pragma unroll 1
  for (int i = s0 + t; i < s1; i += 256) {
    const int p = binned[i];
    const int dlow = p >> 17;
    const int sv = p & 131071;
    const int slot = atomicAdd(&c128[dlow], 1);
    if (slot < CAP) {
      bucket[(nbase + dlow) * CAP + slot] = sv;
    } else {
      const int q = atomicAdd(&ovf[-2], 1);  // ovf[-2] == ovfCnt
      if (q < OVF_CAPN) { ovf[2 * q] = nbase + dlow; ovf[2 * q + 1] = sv; }
    }
  }
  __syncthreads();
  if (t < 128 && nbase + t < NN) {
    const int dc = min(c128[t], CAP);
    cnt[nbase + t] = c128[t];
    // pad to next multiple of 16 with dummy index NN (zero row) for branch-free agg
    const int pad = min((dc + 15) & ~15, CAP);
    int* __restrict__ brow = bucket + (nbase + t) * CAP;
#pragma unroll 1
    for (int q2 = dc; q2 < pad; ++q2) brow[q2] = NN;
  }
}

// cvt (h f32 -> hb bf16 rows) + zero row hb[NN] + x passthrough, one dispatch
__global__ __launch_bounds__(256) void cvtx_k(const float* __restrict__ h,
                                              unsigned* __restrict__ hb,
                                              const float* __restrict__ x,
                                              float* __restrict__ ox) {
  const int b = blockIdx.x;
  const int t = threadIdx.x;
  if (b < 3125) {
    const int i = b * 256 + t;             // 0..799999
    const float4* __restrict__ h4 = reinterpret_cast<const float4*>(h);
    const float4 a = h4[2 * i], c = h4[2 * i + 1];
    uint4 o;
    o.x = pk2(a.x, a.y); o.y = pk2(a.z, a.w);
    o.z = pk2(c.x, c.y); o.w = pk2(c.z, c.w);
    reinterpret_cast<uint4*>(hb)[i] = o;
  } else {
    if (b == 3125 && t < 32) hb[NN * 32 + t] = 0;   // zero row for dummy gathers
    const int i = (b - 3125) * 256 + t;
    if (i < (NN * 3) / 4)
      reinterpret_cast<float4*>(ox)[i] = reinterpret_cast<const float4*>(x)[i];
  }
}

// z[n] = hb[n] + sum_{j->n} hb[j].  Branch-free: bucket rows padded to mult-16 with NN
// (zero row). Wave per node; lane = (slot s = l>>4, group g = l&15); per iter one int4
// index load + 4 unconditional uint2 gathers; shfl_xor(16,32) reduces slots.
__global__ __launch_bounds__(256) void agg_k(const unsigned short* __restrict__ hb,
                                             const int* __restrict__ cnt,
                                             const int* __restrict__ bucket,
                                             unsigned* __restrict__ zbu) {
  const int l = threadIdx.x & 63;
  const int s = l >> 4, g = l & 15;
  int n = blockIdx.x * 4 + (threadIdx.x >> 6);
  n = __builtin_amdgcn_readfirstlane(n);
  if (n >= NN) return;
  const int deg = min(cnt[n], CAP);
  const int nit = (deg + 15) >> 4;   // 16-row padded batches
  const int4* __restrict__ brow4 = reinterpret_cast<const int4*>(bucket + n * CAP);
  const uint2* __restrict__ h2 = reinterpret_cast<const uint2*>(hb);

  // self row: only slot 0 seeds it (others contribute 0)
  const uint2 sv = h2[n * 16 + g];
  const unsigned m0 = (s == 0) ? sv.x : 0u;
  const unsigned m1 = (s == 0) ? sv.y : 0u;
  float a0 = __uint_as_float(m0 << 16);
  float a1 = __uint_as_float(m0 & 0xffff0000u);
  float a2 = __uint_as_float(m1 << 16);
  float a3 = __uint_as_float(m1 & 0xffff0000u);

#pragma unroll 1
  for (int it = 0; it < nit; ++it) {
    const int4 q = brow4[it * 4 + s];   // this slot's 4 row indices
    const uint2 v0 = h2[q.x * 16 + g];
    const uint2 v1 = h2[q.y * 16 + g];
    const uint2 v2 = h2[q.z * 16 + g];
    const uint2 v3 = h2[q.w * 16 + g];
#define ACCU(vv)                                   \
    a0 += __uint_as_float(vv.x << 16);             \
    a1 += __uint_as_float(vv.x & 0xffff0000u);     \
    a2 += __uint_as_float(vv.y << 16);             \
    a3 += __uint_as_float(vv.y & 0xffff0000u);
    ACCU(v0) ACCU(v1) ACCU(v2) ACCU(v3)
#undef ACCU
  }

  // reduce over slots (lane ^16, ^32)
  a0 += __shfl_xor(a0, 16); a1 += __shfl_xor(a1, 16);
  a2 += __shfl_xor(a2, 16); a3 += __shfl_xor(a3, 16);
  a0 += __shfl_xor(a0, 32); a1 += __shfl_xor(a1, 32);
  a2 += __shfl_xor(a2, 32); a3 += __shfl_xor(a3, 32);

  if (s == 0) {
    uint2 o;
    o.x = pk2(a0, a1);
    o.y = pk2(a2, a3);
    reinterpret_cast<uint2*>(zbu)[n * 32 + g] = o;   // zb row: 256B, bf16 in first 128B
  }
}

// Overflow edges (deg > CAP, ~never): CAS-add bf16 halves in zb rows.
__global__ __launch_bounds__(256) void ovf_fix_k(const unsigned short* __restrict__ hb,
                                                 char* __restrict__ zb,
                                                 const int* __restrict__ ovfCnt,
                                                 const int* __restrict__ ovf) {
  const int cv = min(ovfCnt[0], OVF_CAPN);
  const int l = threadIdx.x & 63;
  const int w = threadIdx.x >> 6;
  for (int p = w; p < cv; p += 4) {
    const int d = ovf[2 * p];
    const int s = ovf[2 * p + 1];
    const float add = bf2f(hb[(s << 6) | l]);
    unsigned* wp = reinterpret_cast<unsigned*>(zb + d * 256 + (l >> 1) * 4);
    const bool hi = l & 1;
    unsigned cur = atomicAdd(wp, 0u);  // load
    while (true) {
      const unsigned short hv = hi ? (unsigned short)(cur >> 16) : (unsigned short)(cur & 0xffffu);
      const unsigned short nh = f2bf(bf2f(hv) + add);
      const unsigned nw = hi ? ((cur & 0x0000ffffu) | ((unsigned)nh << 16))
                             : ((cur & 0xffff0000u) | (unsigned)nh);
      const unsigned prev = atomicCAS(wp, cur, nw);
      if (prev == cur) break;
      cur = prev;
    }
  }
}

// MFMA MLP (verified round 7): per 128-node tile, D1^T = W1^T @ Z^T; relu; D2^T = W2^T @ C1^T.
template <int OUTBF>
__global__ __launch_bounds__(256) void mlp_mfma_k(
    const char* __restrict__ zb,        // bf16 z rows, stride 256B
    void* __restrict__ hout,
    const unsigned short* __restrict__ pw1, const float* __restrict__ b1,
    const unsigned short* __restrict__ pw2, const float* __restrict__ b2,
    const float* __restrict__ mask) {
  __shared__ unsigned ldsu[128 * 33];   // 16.9 KB
  const int tid = threadIdx.x;
  const int w = tid >> 6, l = tid & 63, g = l >> 4, mi = l & 15;
  const int m0 = blockIdx.x * 128;
  const int rbase = w * 32;

  // Z^T B-fragments: lane holds z[node(mi)][k = ks*32 + g*8 + j]
  s8v zf[2][2];
#pragma unroll
  for (int tm = 0; tm < 2; ++tm) {
    const int node = m0 + rbase + tm * 16 + mi;
    const int nc = node < NN ? node : NN - 1;
#pragma unroll
    for (int ks = 0; ks < 2; ++ks)
      zf[tm][ks] = *reinterpret_cast<const s8v*>(zb + nc * 256 + (ks * 32 + g * 8) * 2);
  }

  // GEMM1 (C-in = bias)
  f4v acc[4][2];
#pragma unroll
  for (int t = 0; t < 4; ++t) {
    const f4v bv = *reinterpret_cast<const f4v*>(b1 + t * 16 + g * 4);
    acc[t][0] = bv; acc[t][1] = bv;
  }
#pragma unroll
  for (int t = 0; t < 4; ++t) {
#pragma unroll
    for (int ks = 0; ks < 2; ++ks) {
      const s8v wf = *reinterpret_cast<const s8v*>(pw1 + ((t * 2 + ks) * 64 + l) * 8);
#pragma unroll
      for (int tm = 0; tm < 2; ++tm)
        acc[t][tm] = __builtin_amdgcn_mfma_f32_16x16x32_bf16(wf, zf[tm][ks], acc[t][tm], 0, 0, 0);
    }
  }

  // relu + pack -> LDS (unsigned scalar stores; row stride 33 words)
#pragma unroll
  for (int t = 0; t < 4; ++t) {
#pragma unroll
    for (int tm = 0; tm < 2; ++tm) {
      const f4v a = acc[t][tm];
      const int row = rbase + tm * 16 + mi;
      const int base = row * 33 + t * 8 + g * 2;
      ldsu[base]     = pk2(fmaxf(a.x, 0.f), fmaxf(a.y, 0.f));
      ldsu[base + 1] = pk2(fmaxf(a.z, 0.f), fmaxf(a.w, 0.f));
    }
  }
  __syncthreads();

  // GEMM2 B-fragments from LDS
  s8v cf[2][2];
#pragma unroll
  for (int tm = 0; tm < 2; ++tm) {
    const int row = rbase + tm * 16 + mi;
#pragma unroll
    for (int ks = 0; ks < 2; ++ks) {
      const int b0 = row * 33 + ks * 16 + g * 4;
      U8 u8;
      u8.u[0] = ldsu[b0 + 0];
      u8.u[1] = ldsu[b0 + 1];
      u8.u[2] = ldsu[b0 + 2];
      u8.u[3] = ldsu[b0 + 3];
      cf[tm][ks] = u8.s;
    }
  }

  f4v acc2[4][2];
#pragma unroll
  for (int t = 0; t < 4; ++t) {
    const f4v bv = *reinterpret_cast<const f4v*>(b2 + t * 16 + g * 4);
    acc2[t][0] = bv; acc2[t][1] = bv;
  }
#pragma unroll
  for (int t = 0; t < 4; ++t) {
#pragma unroll
    for (int ks = 0; ks < 2; ++ks) {
      const s8v wf = *reinterpret_cast<const s8v*>(pw2 + ((t * 2 + ks) * 64 + l) * 8);
#pragma unroll
      for (int tm = 0; tm < 2; ++tm)
        acc2[t][tm] = __builtin_amdgcn_mfma_f32_16x16x32_bf16(wf, cf[tm][ks], acc2[t][tm], 0, 0, 0);
    }
  }

  // epilogue: direct fragment stores
  if (OUTBF) {
    unsigned* __restrict__ ho = reinterpret_cast<unsigned*>(hout);
#pragma unroll
    for (int tm = 0; tm < 2; ++tm) {
      const int node = m0 + rbase + tm * 16 + mi;
      if (node < NN) {
#pragma unroll
        for (int t = 0; t < 4; ++t) {
          const f4v a = acc2[t][tm];
          const int idx = node * 32 + t * 8 + g * 2;
          uint2 p;
          p.x = pk2(a.x, a.y);
          p.y = pk2(a.z, a.w);
          *reinterpret_cast<uint2*>(&ho[idx]) = p;
        }
      }
    }
  } else {
    float* __restrict__ fo = reinterpret_cast<float*>(hout);
#pragma unroll
    for (int tm = 0; tm < 2; ++tm) {
      const int node = m0 + rbase + tm * 16 + mi;
      if (node < NN) {
        const float mv = mask[node];
#pragma unroll
        for (int t = 0; t < 4; ++t) {
          f4v v = acc2[t][tm];
          v *= mv;
          *reinterpret_cast<f4v*>(fo + node * 64 + t * 16 + g * 4) = v;
        }
      }
    }
  }
}

extern "C" void kernel_launch(void* const* d_in, const int* in_sizes, int n_in,
                              void* d_out, int out_size, void* d_ws, size_t ws_size,
                              hipStream_t stream) {
  (void)in_sizes; (void)n_in; (void)out_size; (void)ws_size;
  const float* h    = (const float*)d_in[0];
  const float* x    = (const float*)d_in[1];
  const int*   ei   = (const int*)d_in[2];
  const float* mask = (const float*)d_in[3];
  const float* W1_0 = (const float*)d_in[4];
  const float* b1_0 = (const float*)d_in[5];
  const float* W2_0 = (const float*)d_in[6];
  const float* b2_0 = (const float*)d_in[7];
  const float* W1_1 = (const float*)d_in[8];
  const float* b1_1 = (const float*)d_in[9];
  const float* W2_1 = (const float*)d_in[10];
  const float* b2_1 = (const float*)d_in[11];
  float* out = (float*)d_out;

  const int* src = ei;       // edge_index[0]
  const int* dst = ei + EE;  // edge_index[1]

  int* wsp       = (int*)d_ws;
  int* binTot    = wsp;
  int* ovfCnt    = wsp + OVFC_OFF;
  int* ovf       = wsp + OVF_OFF;
  int* binStart  = wsp + BSTART_OFF;
  int* cursor    = wsp + CURSOR_OFF;
  int* cnt       = wsp + CNT_OFF;
  int* bucket    = wsp + BUCK_OFF;
  int* binned    = wsp + BINNED_OFF;
  unsigned* hb   = (unsigned*)(wsp + HB_OFF);      // bf16 h (+zero row), later bf16 h1
  unsigned short* pw = (unsigned short*)(wsp + PW_OFF);
  const unsigned short* hbs = (const unsigned short*)hb;
  unsigned* zbu  = (unsigned*)d_out;  // bf16 z rows at node*256B
  char* zb       = (char*)d_out;

  // --- edge structure build (once, reused by both layers) ---
  setup_k<<<1, 256, 0, stream>>>(W1_0, W2_0, W1_1, W2_1, pw, wsp);  // zero + pack
  hist_k<<<256, 256, 0, stream>>>(dst, binTot);
  scan_k<<<1, 1024, 0, stream>>>(binTot, binStart, cursor);
  scatter_k<<<256, 256, 0, stream>>>(src, dst, cursor, binned);
  bucketize_k<<<782, 256, 0, stream>>>(binStart, binned, bucket, cnt, ovf);

  // --- h -> bf16 (+ zero row) + x passthrough (binned dead; region becomes hb) ---
  cvtx_k<<<3418, 256, 0, stream>>>(h, hb, x, out + NN * 64);

  // --- layer 1 ---
  agg_k<<<25000, 256, 0, stream>>>(hbs, cnt, bucket, zbu);
  ovf_fix_k<<<1, 256, 0, stream>>>(hbs, zb, ovfCnt, ovf);
  mlp_mfma_k<1><<<782, 256, 0, stream>>>(zb, hb, pw, b1_0, pw + 4096, b2_0, nullptr);

  // --- layer 2 ---
  agg_k<<<25000, 256, 0, stream>>>(hbs, cnt, bucket, zbu);
  ovf_fix_k<<<1, 256, 0, stream>>>(hbs, zb, ovfCnt, ovf);
  mlp_mfma_k<0><<<782, 256, 0, stream>>>(zb, out, pw + 8192, b1_1, pw + 12288, b2_1, mask);
}

// Round 11
// 146.052 us; speedup vs baseline: 2.0313x; 1.1253x over previous
//
#include <hip/hip_runtime.h>

// GIN block, 2 layers: h = mlp(h + segsum(h[src], dst)); out = (h*mask, x)
// N=100000, E=1600000, D=64.
// Round-11 = round-10 with the bin-capacity bug fixed:
//  - BINCAP 2048 -> 2688. Only 782 of 1024 bins receive edges, so true mean bin
//    load is E/781.25 = 2048 (NOT 1562); 2048 capacity overflowed ~half the bins
//    and blew past OVF_CAPN (dropped edges, absmax 17). 2688 = mean + 14 sigma.
//  - single-pass binning (scatter allocates via global gcur), 2-node-per-wave agg,
//    cvtx / bucketize / mlp_mfma / ovf_fix unchanged.

#define NN 100000
#define EE 1600000
#define CAP 48
#define NBIN 1024
#define BINCAP 2688
#define CHB 6250
#define OVF_CAPN 8000

// ws layout (ints):
//   gcur     @ 0        (1024)   -- init b*BINCAP by setup_k
//   ovfCnt   @ 1024     (1)      -- zeroed by setup_k
//   ovf      @ 1026     (2*8000)
//   cnt      @ 19200    (100000)
//   bucket   @ 119296   (NN*CAP)
//   binned   @ 4919296  (NBIN*BINCAP = 2752512) } binned dead after bucketize ->
//   hb/hb1   @ 4919296  (3200032)               } bf16 h / h1 + zero row at hb[NN]
//   pw       @ 8119328  (16384 shorts)
#define OVFC_OFF   1024
#define OVF_OFF    1026
#define CNT_OFF    19200
#define BUCK_OFF   119296
#define BINNED_OFF 4919296
#define HB_OFF     4919296
#define PW_OFF     8119328

typedef __attribute__((ext_vector_type(8))) short s8v;
typedef __attribute__((ext_vector_type(4))) float f4v;

union U8 { unsigned u[4]; s8v s; };

static __device__ __forceinline__ unsigned short f2bf(float f) {
  unsigned u = __float_as_uint(f);
  return (unsigned short)((u + 0x7FFF + ((u >> 16) & 1)) >> 16);  // RTNE
}
static __device__ __forceinline__ float bf2f(unsigned short s) {
  return __uint_as_float(((unsigned)s) << 16);
}
static __device__ __forceinline__ unsigned pk2(float lo, float hi) {
  return (unsigned)f2bf(lo) | ((unsigned)f2bf(hi) << 16);
}

// setup: gcur[b] = b*BINCAP, ovfCnt = 0, pack W[64][64] f32 row-major -> A-frag bf16:
// pw[m*4096 + ((t*2+ks)*64 + l)*8 + j] = bf16(W[ks*32 + (l>>4)*8 + j][t*16 + (l&15)])
__global__ __launch_bounds__(256) void setup_k(const float* __restrict__ W1a,
                                               const float* __restrict__ W2a,
                                               const float* __restrict__ W1b,
                                               const float* __restrict__ W2b,
                                               unsigned short* __restrict__ pw,
                                               int* __restrict__ wsp) {
  const int t = threadIdx.x;
#pragma unroll
  for (int i = t; i < NBIN; i += 256) wsp[i] = i * BINCAP;  // gcur
  if (t == 0) wsp[OVFC_OFF] = 0;
  const float* Ws[4] = {W1a, W2a, W1b, W2b};
#pragma unroll
  for (int m = 0; m < 4; ++m) {
    const float* __restrict__ W = Ws[m];
#pragma unroll 1
    for (int i = 0; i < 16; ++i) {
      const int e = i * 256 + t;           // 0..4095
      const int j = e & 7;
      const int lv = (e >> 3) & 63;
      const int ks = (e >> 9) & 1;
      const int tt = e >> 10;
      const int k = ks * 32 + (lv >> 4) * 8 + j;
      const int n = tt * 16 + (lv & 15);
      pw[m * 4096 + e] = f2bf(W[k * 64 + n]);
    }
  }
}

// single-pass binning: LDS block-hist -> one global cursor bump per (block,bin) -> scatter
__global__ __launch_bounds__(256) void scatter_k(const int* __restrict__ src,
                                                 const int* __restrict__ dst,
                                                 int* __restrict__ gcur,
                                                 int* __restrict__ binned,
                                                 int* __restrict__ ovf) {
  __shared__ int hist[NBIN], base[NBIN], lcnt[NBIN];
  const int t = threadIdx.x;
#pragma unroll
  for (int b = t; b < NBIN; b += 256) { hist[b] = 0; lcnt[b] = 0; }
  __syncthreads();
  const int s = blockIdx.x * CHB;
#pragma unroll 1
  for (int p = t; p < CHB / 2; p += 256) {
    const int2 dd = *reinterpret_cast<const int2*>(dst + s + 2 * p);
    atomicAdd(&hist[dd.x >> 7], 1);
    atomicAdd(&hist[dd.y >> 7], 1);
  }
  __syncthreads();
#pragma unroll
  for (int b = t; b < NBIN; b += 256) {
    const int c = hist[b];
    base[b] = c ? atomicAdd(&gcur[b], c) : 0;
  }
  __syncthreads();
#pragma unroll 1
  for (int p = t; p < CHB / 2; p += 256) {
    const int i = s + 2 * p;
    const int2 dd = *reinterpret_cast<const int2*>(dst + i);
    const int2 ss = *reinterpret_cast<const int2*>(src + i);
    {
      const int bin = dd.x >> 7;
      const int slot = base[bin] + atomicAdd(&lcnt[bin], 1);
      if (slot < (bin + 1) * BINCAP) {
        binned[slot] = ((dd.x & 127) << 17) | ss.x;
      } else {
        const int q = atomicAdd(&ovf[-2], 1);
        if (q < OVF_CAPN) { ovf[2 * q] = dd.x; ovf[2 * q + 1] = ss.x; }
      }
    }
    {
      const int bin = dd.y >> 7;
      const int slot = base[bin] + atomicAdd(&lcnt[bin], 1);
      if (slot < (bin + 1) * BINCAP) {
        binned[slot] = ((dd.y & 127) << 17) | ss.y;
      } else {
        const int q = atomicAdd(&ovf[-2], 1);
        if (q < OVF_CAPN) { ovf[2 * q] = dd.y; ovf[2 * q + 1] = ss.y; }
      }
    }
  }
}

__global__ __launch_bounds__(256) void bucketize_k(const int* __restrict__ gcur,
                                                   const int* __restrict__ binned,
                                                   int* __restrict__ bucket,
                                                   int* __restrict__ cnt,
                                                   int* __restrict__ ovf) {
  __shared__ int c128[128];
  const int t = threadIdx.x;
  const int bin = blockIdx.x;
  const int nbase = bin << 7;
  if (t < 128) c128[t] = 0;
  __syncthreads();
  const int s0 = bin * BINCAP;
  const int s1 = min(gcur[bin], s0 + BINCAP);
#pragma unroll 1
  for (int i = s0 + t; i < s1; i += 256) {
    const int p = binned[i];
    const int dlow = p >> 17;
    const int sv = p & 131071;
    const int slot = atomicAdd(&c128[dlow], 1);
    if (slot < CAP) {
      bucket[(nbase + dlow) * CAP + slot] = sv;
    } else {
      const int q = atomicAdd(&ovf[-2], 1);  // ovf[-2] == ovfCnt
      if (q < OVF_CAPN) { ovf[2 * q] = nbase + dlow; ovf[2 * q + 1] = sv; }
    }
  }
  __syncthreads();
  if (t < 128 && nbase + t < NN) {
    const int dc = min(c128[t], CAP);
    cnt[nbase + t] = c128[t];
    // pad to next multiple of 16 with dummy index NN (zero row) for branch-free agg
    const int pad = min((dc + 15) & ~15, CAP);
    int* __restrict__ brow = bucket + (nbase + t) * CAP;
#pragma unroll 1
    for (int q2 = dc; q2 < pad; ++q2) brow[q2] = NN;
  }
}

// cvt (h f32 -> hb bf16 rows) + zero row hb[NN] + x passthrough, one dispatch
__global__ __launch_bounds__(256) void cvtx_k(const float* __restrict__ h,
                                              unsigned* __restrict__ hb,
                                              const float* __restrict__ x,
                                              float* __restrict__ ox) {
  const int b = blockIdx.x;
  const int t = threadIdx.x;
  if (b < 3125) {
    const int i = b * 256 + t;             // 0..799999
    const float4* __restrict__ h4 = reinterpret_cast<const float4*>(h);
    const float4 a = h4[2 * i], c = h4[2 * i + 1];
    uint4 o;
    o.x = pk2(a.x, a.y); o.y = pk2(a.z, a.w);
    o.z = pk2(c.x, c.y); o.w = pk2(c.z, c.w);
    reinterpret_cast<uint4*>(hb)[i] = o;
  } else {
    if (b == 3125 && t < 32) hb[NN * 32 + t] = 0;   // zero row for dummy gathers
    const int i = (b - 3125) * 256 + t;
    if (i < (NN * 3) / 4)
      reinterpret_cast<float4*>(ox)[i] = reinterpret_cast<const float4*>(x)[i];
  }
}

// z[n] = hb[n] + sum_{j->n} hb[j].  Branch-free padded gather; TWO nodes per wave
// (dual accumulators, interleaved loads ~doubles memory-level parallelism).
// lane = (slot s = l>>4, group g = l&15); per iter per node: one int4 index load +
// 4 unconditional uint2 gathers; shfl_xor(16,32) reduces slots.
__global__ __launch_bounds__(256) void agg_k(const unsigned short* __restrict__ hb,
                                             const int* __restrict__ cnt,
                                             const int* __restrict__ bucket,
                                             unsigned* __restrict__ zbu) {
  const int l = threadIdx.x & 63;
  const int s = l >> 4, g = l & 15;
  int nb = blockIdx.x * 8 + (threadIdx.x >> 6) * 2;   // 12500*8 = 100000 exact
  nb = __builtin_amdgcn_readfirstlane(nb);
  const int n0 = nb, n1 = nb + 1;

  const int2 c2 = *reinterpret_cast<const int2*>(cnt + n0);  // n0 even -> aligned
  const int deg0 = min(c2.x, CAP), deg1 = min(c2.y, CAP);
  const int nit0 = (deg0 + 15) >> 4, nit1 = (deg1 + 15) >> 4;
  const int nc = min(nit0, nit1);

  const int4* __restrict__ br0 = reinterpret_cast<const int4*>(bucket + n0 * CAP);
  const int4* __restrict__ br1 = reinterpret_cast<const int4*>(bucket + n1 * CAP);
  const uint2* __restrict__ h2 = reinterpret_cast<const uint2*>(hb);

  // self rows: only slot 0 seeds
  const uint2 sv0 = h2[n0 * 16 + g];
  const uint2 sv1 = h2[n1 * 16 + g];
  const unsigned p00 = (s == 0) ? sv0.x : 0u, p01 = (s == 0) ? sv0.y : 0u;
  const unsigned p10 = (s == 0) ? sv1.x : 0u, p11 = (s == 0) ? sv1.y : 0u;
  float a0 = __uint_as_float(p00 << 16), a1 = __uint_as_float(p00 & 0xffff0000u);
  float a2 = __uint_as_float(p01 << 16), a3 = __uint_as_float(p01 & 0xffff0000u);
  float b0 = __uint_as_float(p10 << 16), b1 = __uint_as_float(p10 & 0xffff0000u);
  float b2 = __uint_as_float(p11 << 16), b3 = __uint_as_float(p11 & 0xffff0000u);

#define ACCA(vv)                                   \
    a0 += __uint_as_float(vv.x << 16);             \
    a1 += __uint_as_float(vv.x & 0xffff0000u);     \
    a2 += __uint_as_float(vv.y << 16);             \
    a3 += __uint_as_float(vv.y & 0xffff0000u);
#define ACCB(vv)                                   \
    b0 += __uint_as_float(vv.x << 16);             \
    b1 += __uint_as_float(vv.x & 0xffff0000u);     \
    b2 += __uint_as_float(vv.y << 16);             \
    b3 += __uint_as_float(vv.y & 0xffff0000u);

#pragma unroll 1
  for (int it = 0; it < nc; ++it) {                 // interleaved: 2 idx + 8 gathers in flight
    const int4 q0 = br0[it * 4 + s];
    const int4 q1 = br1[it * 4 + s];
    const uint2 v0 = h2[q0.x * 16 + g];
    const uint2 v1 = h2[q0.y * 16 + g];
    const uint2 v2 = h2[q0.z * 16 + g];
    const uint2 v3 = h2[q0.w * 16 + g];
    const uint2 w0 = h2[q1.x * 16 + g];
    const uint2 w1 = h2[q1.y * 16 + g];
    const uint2 w2 = h2[q1.z * 16 + g];
    const uint2 w3 = h2[q1.w * 16 + g];
    ACCA(v0) ACCA(v1) ACCA(v2) ACCA(v3)
    ACCB(w0) ACCB(w1) ACCB(w2) ACCB(w3)
  }
#pragma unroll 1
  for (int it = nc; it < nit0; ++it) {              // wave-uniform tail, node 0
    const int4 q0 = br0[it * 4 + s];
    const uint2 v0 = h2[q0.x * 16 + g];
    const uint2 v1 = h2[q0.y * 16 + g];
    const uint2 v2 = h2[q0.z * 16 + g];
    const uint2 v3 = h2[q0.w * 16 + g];
    ACCA(v0) ACCA(v1) ACCA(v2) ACCA(v3)
  }
#pragma unroll 1
  for (int it = nc; it < nit1; ++it) {              // wave-uniform tail, node 1
    const int4 q1 = br1[it * 4 + s];
    const uint2 w0 = h2[q1.x * 16 + g];
    const uint2 w1 = h2[q1.y * 16 + g];
    const uint2 w2 = h2[q1.z * 16 + g];
    const uint2 w3 = h2[q1.w * 16 + g];
    ACCB(w0) ACCB(w1) ACCB(w2) ACCB(w3)
  }
#undef ACCA
#undef ACCB

  // reduce over slots (lane ^16, ^32)
  a0 += __shfl_xor(a0, 16); a1 += __shfl_xor(a1, 16);
  a2 += __shfl_xor(a2, 16); a3 += __shfl_xor(a3, 16);
  a0 += __shfl_xor(a0, 32); a1 += __shfl_xor(a1, 32);
  a2 += __shfl_xor(a2, 32); a3 += __shfl_xor(a3, 32);
  b0 += __shfl_xor(b0, 16); b1 += __shfl_xor(b1, 16);
  b2 += __shfl_xor(b2, 16); b3 += __shfl_xor(b3, 16);
  b0 += __shfl_xor(b0, 32); b1 += __shfl_xor(b1, 32);
  b2 += __shfl_xor(b2, 32); b3 += __shfl_xor(b3, 32);

  if (s == 0) {
    uint2 o0, o1;
    o0.x = pk2(a0, a1); o0.y = pk2(a2, a3);
    o1.x = pk2(b0, b1); o1.y = pk2(b2, b3);
    reinterpret_cast<uint2*>(zbu)[n0 * 32 + g] = o0;  // zb row: 256B, bf16 in first 128B
    reinterpret_cast<uint2*>(zbu)[n1 * 32 + g] = o1;
  }
}

// Overflow edges (deg > CAP or bin overflow, ~never): CAS-add bf16 halves in zb rows.
__global__ __launch_bounds__(256) void ovf_fix_k(const unsigned short* __restrict__ hb,
                                                 char* __restrict__ zb,
                                                 const int* __restrict__ ovfCnt,
                                                 const int* __restrict__ ovf) {
  const int cv = min(ovfCnt[0], OVF_CAPN);
  const int l = threadIdx.x & 63;
  const int w = threadIdx.x >> 6;
  for (int p = w; p < cv; p += 4) {
    const int d = ovf[2 * p];
    const int s = ovf[2 * p + 1];
    const float add = bf2f(hb[(s << 6) | l]);
    unsigned* wp = reinterpret_cast<unsigned*>(zb + d * 256 + (l >> 1) * 4);
    const bool hi = l & 1;
    unsigned cur = atomicAdd(wp, 0u);  // load
    while (true) {
      const unsigned short hv = hi ? (unsigned short)(cur >> 16) : (unsigned short)(cur & 0xffffu);
      const unsigned short nh = f2bf(bf2f(hv) + add);
      const unsigned nw = hi ? ((cur & 0x0000ffffu) | ((unsigned)nh << 16))
                             : ((cur & 0xffff0000u) | (unsigned)nh);
      const unsigned prev = atomicCAS(wp, cur, nw);
      if (prev == cur) break;
      cur = prev;
    }
  }
}

// MFMA MLP (verified round 7): per 128-node tile, D1^T = W1^T @ Z^T; relu; D2^T = W2^T @ C1^T.
template <int OUTBF>
__global__ __launch_bounds__(256) void mlp_mfma_k(
    const char* __restrict__ zb,        // bf16 z rows, stride 256B
    void* __restrict__ hout,
    const unsigned short* __restrict__ pw1, const float* __restrict__ b1,
    const unsigned short* __restrict__ pw2, const float* __restrict__ b2,
    const float* __restrict__ mask) {
  __shared__ unsigned ldsu[128 * 33];   // 16.9 KB
  const int tid = threadIdx.x;
  const int w = tid >> 6, l = tid & 63, g = l >> 4, mi = l & 15;
  const int m0 = blockIdx.x * 128;
  const int rbase = w * 32;

  // Z^T B-fragments: lane holds z[node(mi)][k = ks*32 + g*8 + j]
  s8v zf[2][2];
#pragma unroll
  for (int tm = 0; tm < 2; ++tm) {
    const int node = m0 + rbase + tm * 16 + mi;
    const int nc = node < NN ? node : NN - 1;
#pragma unroll
    for (int ks = 0; ks < 2; ++ks)
      zf[tm][ks] = *reinterpret_cast<const s8v*>(zb + nc * 256 + (ks * 32 + g * 8) * 2);
  }

  // GEMM1 (C-in = bias)
  f4v acc[4][2];
#pragma unroll
  for (int t = 0; t < 4; ++t) {
    const f4v bv = *reinterpret_cast<const f4v*>(b1 + t * 16 + g * 4);
    acc[t][0] = bv; acc[t][1] = bv;
  }
#pragma unroll
  for (int t = 0; t < 4; ++t) {
#pragma unroll
    for (int ks = 0; ks < 2; ++ks) {
      const s8v wf = *reinterpret_cast<const s8v*>(pw1 + ((t * 2 + ks) * 64 + l) * 8);
#pragma unroll
      for (int tm = 0; tm < 2; ++tm)
        acc[t][tm] = __builtin_amdgcn_mfma_f32_16x16x32_bf16(wf, zf[tm][ks], acc[t][tm], 0, 0, 0);
    }
  }

  // relu + pack -> LDS (unsigned scalar stores; row stride 33 words)
#pragma unroll
  for (int t = 0; t < 4; ++t) {
#pragma unroll
    for (int tm = 0; tm < 2; ++tm) {
      const f4v a = acc[t][tm];
      const int row = rbase + tm * 16 + mi;
      const int base = row * 33 + t * 8 + g * 2;
      ldsu[base]     = pk2(fmaxf(a.x, 0.f), fmaxf(a.y, 0.f));
      ldsu[base + 1] = pk2(fmaxf(a.z, 0.f), fmaxf(a.w, 0.f));
    }
  }
  __syncthreads();

  // GEMM2 B-fragments from LDS
  s8v cf[2][2];
#pragma unroll
  for (int tm = 0; tm < 2; ++tm) {
    const int row = rbase + tm * 16 + mi;
#pragma unroll
    for (int ks = 0; ks < 2; ++ks) {
      const int b0 = row * 33 + ks * 16 + g * 4;
      U8 u8;
      u8.u[0] = ldsu[b0 + 0];
      u8.u[1] = ldsu[b0 + 1];
      u8.u[2] = ldsu[b0 + 2];
      u8.u[3] = ldsu[b0 + 3];
      cf[tm][ks] = u8.s;
    }
  }

  f4v acc2[4][2];
#pragma unroll
  for (int t = 0; t < 4; ++t) {
    const f4v bv = *reinterpret_cast<const f4v*>(b2 + t * 16 + g * 4);
    acc2[t][0] = bv; acc2[t][1] = bv;
  }
#pragma unroll
  for (int t = 0; t < 4; ++t) {
#pragma unroll
    for (int ks = 0; ks < 2; ++ks) {
      const s8v wf = *reinterpret_cast<const s8v*>(pw2 + ((t * 2 + ks) * 64 + l) * 8);
#pragma unroll
      for (int tm = 0; tm < 2; ++tm)
        acc2[t][tm] = __builtin_amdgcn_mfma_f32_16x16x32_bf16(wf, cf[tm][ks], acc2[t][tm], 0, 0, 0);
    }
  }

  // epilogue: direct fragment stores
  if (OUTBF) {
    unsigned* __restrict__ ho = reinterpret_cast<unsigned*>(hout);
#pragma unroll
    for (int tm = 0; tm < 2; ++tm) {
      const int node = m0 + rbase + tm * 16 + mi;
      if (node < NN) {
#pragma unroll
        for (int t = 0; t < 4; ++t) {
          const f4v a = acc2[t][tm];
          const int idx = node * 32 + t * 8 + g * 2;
          uint2 p;
          p.x = pk2(a.x, a.y);
          p.y = pk2(a.z, a.w);
          *reinterpret_cast<uint2*>(&ho[idx]) = p;
        }
      }
    }
  } else {
    float* __restrict__ fo = reinterpret_cast<float*>(hout);
#pragma unroll
    for (int tm = 0; tm < 2; ++tm) {
      const int node = m0 + rbase + tm * 16 + mi;
      if (node < NN) {
        const float mv = mask[node];
#pragma unroll
        for (int t = 0; t < 4; ++t) {
          f4v v = acc2[t][tm];
          v *= mv;
          *reinterpret_cast<f4v*>(fo + node * 64 + t * 16 + g * 4) = v;
        }
      }
    }
  }
}

extern "C" void kernel_launch(void* const* d_in, const int* in_sizes, int n_in,
                              void* d_out, int out_size, void* d_ws, size_t ws_size,
                              hipStream_t stream) {
  (void)in_sizes; (void)n_in; (void)out_size; (void)ws_size;
  const float* h    = (const float*)d_in[0];
  const float* x    = (const float*)d_in[1];
  const int*   ei   = (const int*)d_in[2];
  const float* mask = (const float*)d_in[3];
  const float* W1_0 = (const float*)d_in[4];
  const float* b1_0 = (const float*)d_in[5];
  const float* W2_0 = (const float*)d_in[6];
  const float* b2_0 = (const float*)d_in[7];
  const float* W1_1 = (const float*)d_in[8];
  const float* b1_1 = (const float*)d_in[9];
  const float* W2_1 = (const float*)d_in[10];
  const float* b2_1 = (const float*)d_in[11];
  float* out = (float*)d_out;

  const int* src = ei;       // edge_index[0]
  const int* dst = ei + EE;  // edge_index[1]

  int* wsp       = (int*)d_ws;
  int* gcur      = wsp;
  int* ovfCnt    = wsp + OVFC_OFF;
  int* ovf       = wsp + OVF_OFF;
  int* cnt       = wsp + CNT_OFF;
  int* bucket    = wsp + BUCK_OFF;
  int* binned    = wsp + BINNED_OFF;
  unsigned* hb   = (unsigned*)(wsp + HB_OFF);      // bf16 h (+zero row), later bf16 h1
  unsigned short* pw = (unsigned short*)(wsp + PW_OFF);
  const unsigned short* hbs = (const unsigned short*)hb;
  unsigned* zbu  = (unsigned*)d_out;  // bf16 z rows at node*256B
  char* zb       = (char*)d_out;

  // --- edge structure build (once, reused by both layers) ---
  setup_k<<<1, 256, 0, stream>>>(W1_0, W2_0, W1_1, W2_1, pw, wsp);  // gcur init + pack
  scatter_k<<<256, 256, 0, stream>>>(src, dst, gcur, binned, ovf);
  bucketize_k<<<782, 256, 0, stream>>>(gcur, binned, bucket, cnt, ovf);

  // --- h -> bf16 (+ zero row) + x passthrough (binned dead; region becomes hb) ---
  cvtx_k<<<3418, 256, 0, stream>>>(h, hb, x, out + NN * 64);

  // --- layer 1 ---
  agg_k<<<12500, 256, 0, stream>>>(hbs, cnt, bucket, zbu);
  ovf_fix_k<<<1, 256, 0, stream>>>(hbs, zb, ovfCnt, ovf);
  mlp_mfma_k<1><<<782, 256, 0, stream>>>(zb, hb, pw, b1_0, pw + 4096, b2_0, nullptr);

  // --- layer 2 ---
  agg_k<<<12500, 256, 0, stream>>>(hbs, cnt, bucket, zbu);
  ovf_fix_k<<<1, 256, 0, stream>>>(hbs, zb, ovfCnt, ovf);
  mlp_mfma_k<0><<<782, 256, 0, stream>>>(zb, out, pw + 8192, b1_1, pw + 12288, b2_1, mask);
}